// Round 1
// baseline (2192.406 us; speedup 1.0000x reference)
//
#include <hip/hip_runtime.h>
#include <math.h>

#define QLEN 1024
#define MLEN 1024
#define KLEN 2048
#define BSZc 2
#define NH 16
#define DH 64
#define DM 1024
#define DI 4096

// ---------------------------------------------------------------------------
// Generic f32 GEMM: C = A @ B^T (+bias, +relu), A: MxK rowmajor, B: NxK rowmajor
// AMODE 0: A = A0 (plain). AMODE 1: A = cat(mems=A0, w=A1) rows (klen,bsz) flat.
// EMODE 0: plain C0[m*N+n]. EMODE 1: qkv scatter -> Qac/Qbd/K/V head-major.
// EMODE 2: r_head_k scatter -> R[h][klen][dh].
// ACT 1: relu.
// ---------------------------------------------------------------------------
template<int AMODE, int EMODE, int ACT>
__global__ __launch_bounds__(256)
void gemm64(const float* __restrict__ A0, const float* __restrict__ A1,
            const float* __restrict__ B, const float* __restrict__ bias,
            float* __restrict__ C0, float* __restrict__ C1,
            float* __restrict__ C2, float* __restrict__ C3,
            const float* __restrict__ rwb, const float* __restrict__ rrb,
            int M, int N, int K)
{
    __shared__ float As[16][68];   // [k][m], stride 68 -> 2-way (free) on write
    __shared__ float Bs[16][68];   // [k][n]

    const int tid = threadIdx.x;
    const int m0 = blockIdx.x * 64;
    const int n0 = blockIdx.y * 64;
    const int tm = ((tid >> 4) & 15) << 2;   // 0..60
    const int tn = (tid & 15) << 2;          // 0..60
    const int sm = tid >> 2;                 // staging row 0..63
    const int sk = (tid & 3) << 2;           // staging k 0,4,8,12

    float acc[4][4];
#pragma unroll
    for (int i2 = 0; i2 < 4; ++i2)
#pragma unroll
        for (int j2 = 0; j2 < 4; ++j2) acc[i2][j2] = 0.f;

    const int arow = m0 + sm;
    const float* aptr;
    if (AMODE == 0) {
        aptr = A0 + (size_t)arow * K + sk;
    } else {
        aptr = (arow < KLEN) ? (A0 + (size_t)arow * K + sk)
                             : (A1 + (size_t)(arow - KLEN) * K + sk);
    }
    const float* bptr = B + (size_t)(n0 + sm) * K + sk;

    for (int k0 = 0; k0 < K; k0 += 16) {
        float4 av = *(const float4*)(aptr + k0);
        float4 bv = *(const float4*)(bptr + k0);
        __syncthreads();   // previous iteration's reads done
        As[sk + 0][sm] = av.x; As[sk + 1][sm] = av.y;
        As[sk + 2][sm] = av.z; As[sk + 3][sm] = av.w;
        Bs[sk + 0][sm] = bv.x; Bs[sk + 1][sm] = bv.y;
        Bs[sk + 2][sm] = bv.z; Bs[sk + 3][sm] = bv.w;
        __syncthreads();
#pragma unroll
        for (int kk = 0; kk < 16; ++kk) {
            float4 a4 = *(const float4*)&As[kk][tm];
            float4 b4 = *(const float4*)&Bs[kk][tn];
            float aa[4] = {a4.x, a4.y, a4.z, a4.w};
            float bb2[4] = {b4.x, b4.y, b4.z, b4.w};
#pragma unroll
            for (int i2 = 0; i2 < 4; ++i2)
#pragma unroll
                for (int j2 = 0; j2 < 4; ++j2)
                    acc[i2][j2] = fmaf(aa[i2], bb2[j2], acc[i2][j2]);
        }
    }

#pragma unroll
    for (int i2 = 0; i2 < 4; ++i2) {
        const int m = m0 + tm + i2;
#pragma unroll
        for (int j2 = 0; j2 < 4; ++j2) {
            const int n = n0 + tn + j2;
            float v = acc[i2][j2];
            if (EMODE == 0) {
                if (bias) v += bias[n];
                if (ACT == 1) v = fmaxf(v, 0.f);
                C0[(size_t)m * N + n] = v;
            } else if (EMODE == 1) {
                const int j = m >> 1, b = m & 1;
                const int part = n >> 10, hh = (n >> 6) & 15, d = n & 63;
                if (part == 0) {
                    if (j >= MLEN) {
                        const int qi = j - MLEN;
                        const size_t qidx = (((size_t)(b * NH + hh)) * QLEN + qi) * DH + d;
                        C0[qidx] = v + rwb[hh * DH + d];   // Qac = wq + r_w_bias
                        C1[qidx] = v + rrb[hh * DH + d];   // Qbd = wq + r_r_bias
                    }
                } else if (part == 1) {
                    C2[(((size_t)(b * NH + hh)) * KLEN + j) * DH + d] = v;  // K
                } else {
                    C3[(((size_t)(b * NH + hh)) * KLEN + j) * DH + d] = v;  // V
                }
            } else {  // EMODE 2
                const int hh = n >> 6, d = n & 63;
                C0[(((size_t)hh) * KLEN + m) * DH + d] = v;                 // R
            }
        }
    }
}

// ---------------------------------------------------------------------------
// Flash attention with TransformerXL relative-position shift.
// score(i,j) = (Qac[i]·K[j] + Qbd[i]·R[j+QLEN-1-i]) * scale, valid j <= i+MLEN
// (the rel_shift OOB region is exactly the masked region -> no zeros needed)
// Block = 256 threads = 4 waves; wave w owns query row i = i0+w of head (b,h).
// ---------------------------------------------------------------------------
__global__ __launch_bounds__(256)
void attn_flash(const float* __restrict__ Qac, const float* __restrict__ Qbd,
                const float* __restrict__ Kb, const float* __restrict__ Vb,
                const float* __restrict__ Rb, float* __restrict__ AV)
{
    __shared__ float Kc[64][65];    // stride 65 -> conflict-free scalar reads
    __shared__ float Rc[68][65];    // 64 + (4-1) + 1 window rows
    __shared__ float qa[4][64];
    __shared__ float qb[4][64];
    __shared__ float pb[4][64];

    const int tid  = threadIdx.x;
    const int lane = tid & 63;
    const int w    = tid >> 6;
    const int i0   = blockIdx.x << 2;     // 4 query rows per block
    const int bh   = blockIdx.y;          // b*NH + h
    const int h    = bh & 15;
    const int b    = bh >> 4;
    const int i    = i0 + w;

    const float* Kh = Kb + (size_t)bh * KLEN * DH;
    const float* Vh = Vb + (size_t)bh * KLEN * DH;
    const float* Rh = Rb + (size_t)h  * KLEN * DH;

    {
        const size_t q = (((size_t)bh) * QLEN + i) * DH + lane;
        qa[w][lane] = Qac[q];
        qb[w][lane] = Qbd[q];
    }

    float m_run = -__builtin_inff();
    float l_run = 0.f;
    float o     = 0.f;                    // lane owns output dim d = lane

    const int jmax_me  = i + MLEN;        // inclusive
    const int jmax_blk = i0 + 3 + MLEN;   // uniform loop bound over block
    const int rbase    = 1020 - i0;       // Rc[0] global row offset (rel. j0)
    const int rrow     = (3 - w) + lane;  // this wave's Rc row for its lane

    for (int j0 = 0; j0 <= jmax_blk; j0 += 64) {
        __syncthreads();  // prior reads of Kc/Rc/pb done before restage
        // stage K chunk: 64 rows x 64
#pragma unroll
        for (int t = 0; t < 4; ++t) {
            const int f = tid + t * 256;          // 0..1023 float4s
            const int row = f >> 4, c4 = (f & 15) << 2;
            const float4 v4 = *(const float4*)(Kh + (size_t)(j0 + row) * DH + c4);
            Kc[row][c4 + 0] = v4.x; Kc[row][c4 + 1] = v4.y;
            Kc[row][c4 + 2] = v4.z; Kc[row][c4 + 3] = v4.w;
        }
        // stage R window: 68 rows (clamped; clamped rows only feed masked lanes)
#pragma unroll
        for (int t = 0; t < 5; ++t) {
            const int f = tid + t * 256;
            if (f < 68 * 16) {
                const int row = f >> 4, c4 = (f & 15) << 2;
                int g = j0 + rbase + row;
                g = (g > KLEN - 1) ? (KLEN - 1) : g;
                const float4 v4 = *(const float4*)(Rh + (size_t)g * DH + c4);
                Rc[row][c4 + 0] = v4.x; Rc[row][c4 + 1] = v4.y;
                Rc[row][c4 + 2] = v4.z; Rc[row][c4 + 3] = v4.w;
            }
        }
        __syncthreads();

        // scores: lane handles j = j0 + lane
        float sac = 0.f, sbd = 0.f;
#pragma unroll
        for (int d = 0; d < 64; ++d) {
            sac = fmaf(qa[w][d], Kc[lane][d], sac);
            sbd = fmaf(qb[w][d], Rc[rrow][d], sbd);
        }
        float s = (sac + sbd) * 0.125f;
        const int j = j0 + lane;
        if (j > jmax_me) s = -3.0e38f;

        // online softmax (wave-uniform row state)
        float mx = s;
#pragma unroll
        for (int off = 32; off > 0; off >>= 1)
            mx = fmaxf(mx, __shfl_xor(mx, off, 64));
        const float m_new = fmaxf(m_run, mx);
        const float p = __expf(s - m_new);
        float ps = p;
#pragma unroll
        for (int off = 32; off > 0; off >>= 1)
            ps += __shfl_xor(ps, off, 64);
        const float alpha = __expf(m_run - m_new);
        l_run = l_run * alpha + ps;
        o *= alpha;
        m_run = m_new;

        pb[w][lane] = p;
        __syncthreads();

        // PV: lane = output dim; V reads coalesced across lanes
        const float* vp = Vh + (size_t)j0 * DH + lane;
#pragma unroll 8
        for (int l2 = 0; l2 < 64; ++l2)
            o = fmaf(pb[w][l2], vp[(size_t)l2 * DH], o);
    }

    // attn_vec row-major (i,b) x (h*64+d)
    AV[(((size_t)i) * BSZc + b) * DM + h * DH + lane] = o / l_run;
}

// ---------------------------------------------------------------------------
// out = LayerNorm(X + Y) * g + b ; one block per row of 1024
// ---------------------------------------------------------------------------
__global__ __launch_bounds__(256)
void add_ln(const float* __restrict__ X, const float* __restrict__ Y,
            const float* __restrict__ gg, const float* __restrict__ bb,
            float* __restrict__ out)
{
    const int row  = blockIdx.x;
    const int tid  = threadIdx.x;
    const int lane = tid & 63;
    const int w    = tid >> 6;
    __shared__ float ssum[4], ssq[4];

    const float4 xv = ((const float4*)(X + (size_t)row * DM))[tid];
    const float4 yv = ((const float4*)(Y + (size_t)row * DM))[tid];
    const float v0 = xv.x + yv.x, v1 = xv.y + yv.y;
    const float v2 = xv.z + yv.z, v3 = xv.w + yv.w;
    float s = v0 + v1 + v2 + v3;
    float q = v0 * v0 + v1 * v1 + v2 * v2 + v3 * v3;
#pragma unroll
    for (int off = 32; off > 0; off >>= 1) {
        s += __shfl_xor(s, off, 64);
        q += __shfl_xor(q, off, 64);
    }
    if (lane == 0) { ssum[w] = s; ssq[w] = q; }
    __syncthreads();
    s = ssum[0] + ssum[1] + ssum[2] + ssum[3];
    q = ssq[0] + ssq[1] + ssq[2] + ssq[3];
    const float mean = s * (1.f / DM);
    const float var  = q * (1.f / DM) - mean * mean;
    const float rs   = rsqrtf(var + 1e-5f);
    const float4 g4 = ((const float4*)gg)[tid];
    const float4 b4 = ((const float4*)bb)[tid];
    float4 ov;
    ov.x = (v0 - mean) * rs * g4.x + b4.x;
    ov.y = (v1 - mean) * rs * g4.y + b4.y;
    ov.z = (v2 - mean) * rs * g4.z + b4.z;
    ov.w = (v3 - mean) * rs * g4.w + b4.w;
    ((float4*)(out + (size_t)row * DM))[tid] = ov;
}

// ---------------------------------------------------------------------------
extern "C" void kernel_launch(void* const* d_in, const int* in_sizes, int n_in,
                              void* d_out, int out_size, void* d_ws, size_t ws_size,
                              hipStream_t stream)
{
    (void)in_sizes; (void)n_in; (void)out_size; (void)ws_size;
    const float* w      = (const float*)d_in[0];
    const float* r      = (const float*)d_in[1];
    const float* mems   = (const float*)d_in[2];
    // d_in[3] = attn_mask: deterministic (j > i + MLEN), recomputed analytically
    const float* qkv_w  = (const float*)d_in[4];
    const float* rnet_w = (const float*)d_in[5];
    const float* o_w    = (const float*)d_in[6];
    const float* r_r_b  = (const float*)d_in[7];
    const float* r_w_b  = (const float*)d_in[8];
    const float* ln1g   = (const float*)d_in[9];
    const float* ln1b   = (const float*)d_in[10];
    const float* ffw1   = (const float*)d_in[11];
    const float* ffb1   = (const float*)d_in[12];
    const float* ffw2   = (const float*)d_in[13];
    const float* ffb2   = (const float*)d_in[14];
    const float* ln2g   = (const float*)d_in[15];
    const float* ln2b   = (const float*)d_in[16];
    float* out = (float*)d_out;

    float* ws = (float*)d_ws;
    const size_t MEG = 1024 * 1024;
    float* Qac  = ws + 0 * MEG;    // 2M floats [b][h][qlen][dh]
    float* Qbd  = ws + 2 * MEG;    // 2M
    float* Kbuf = ws + 4 * MEG;    // 4M [b][h][klen][dh]
    float* Vbuf = ws + 8 * MEG;    // 4M
    float* Rbuf = ws + 12 * MEG;   // 2M [h][klen][dh]
    float* AVec = ws + 14 * MEG;   // 2M (i,b) x 1024
    // phase 2 reuse (Q/K/V/R dead after attention):
    float* AOut = ws + 0 * MEG;    // 2M
    float* Hbuf = ws + 2 * MEG;    // 2M
    float* FF   = ws + 4 * MEG;    // 8M (2048 x 4096)
    float* Core = ws + 12 * MEG;   // 2M
    // total: 16M floats = 64 MiB

    dim3 blk(256);

    // 1. QKV projection: cat(mems,w) @ qkv_w^T, scattered into Qac/Qbd/K/V
    gemm64<1, 1, 0><<<dim3(64, 48), blk, 0, stream>>>(
        mems, w, qkv_w, nullptr, Qac, Qbd, Kbuf, Vbuf, r_w_b, r_r_b,
        2 * KLEN, 3 * DM, DM);

    // 2. r_head_k = r @ r_net_w^T -> R[h][klen][dh]
    gemm64<0, 2, 0><<<dim3(32, 16), blk, 0, stream>>>(
        r, nullptr, rnet_w, nullptr, Rbuf, nullptr, nullptr, nullptr,
        nullptr, nullptr, KLEN, DM, DM);

    // 3. flash attention with rel-shift
    attn_flash<<<dim3(QLEN / 4, BSZc * NH), blk, 0, stream>>>(
        Qac, Qbd, Kbuf, Vbuf, Rbuf, AVec);

    // 4. output projection
    gemm64<0, 0, 0><<<dim3(32, 16), blk, 0, stream>>>(
        AVec, nullptr, o_w, nullptr, AOut, nullptr, nullptr, nullptr,
        nullptr, nullptr, 2 * QLEN, DM, DM);

    // 5. h = LN(w + attn_out)
    add_ln<<<dim3(2 * QLEN), blk, 0, stream>>>(w, AOut, ln1g, ln1b, Hbuf);

    // 6. FF1: relu(h @ ff_w1^T + b1)
    gemm64<0, 0, 1><<<dim3(32, 64), blk, 0, stream>>>(
        Hbuf, nullptr, ffw1, ffb1, FF, nullptr, nullptr, nullptr,
        nullptr, nullptr, 2 * QLEN, DI, DM);

    // 7. FF2: ff_act @ ff_w2^T + b2
    gemm64<0, 0, 0><<<dim3(32, 16), blk, 0, stream>>>(
        FF, nullptr, ffw2, ffb2, Core, nullptr, nullptr, nullptr,
        nullptr, nullptr, 2 * QLEN, DM, DI);

    // 8. out = LN(h + core)
    add_ln<<<dim3(2 * QLEN), blk, 0, stream>>>(Hbuf, Core, ln2g, ln2b, out);
}

// Round 2
// 1248.411 us; speedup vs baseline: 1.7562x; 1.7562x over previous
//
#include <hip/hip_runtime.h>
#include <math.h>

#define QLEN 1024
#define MLEN 1024
#define KLEN 2048
#define BSZc 2
#define NH 16
#define DH 64
#define DM 1024
#define DI 4096

typedef unsigned short ushort_t;
typedef __attribute__((ext_vector_type(8))) short short8;
typedef __attribute__((ext_vector_type(4))) float f32x4;

__device__ __forceinline__ ushort_t f2bf(float x) {
    unsigned int u = __float_as_uint(x);
    unsigned int r = (u + 0x7FFFu + ((u >> 16) & 1u)) >> 16;
    return (ushort_t)r;
}

// ---------------------------------------------------------------------------
// f32 GEMM: C = A @ B^T (+bias,+relu). A: MxK rowmajor, B: NxK rowmajor.
// AMODE 1: A = cat(mems=A0, w=A1). EMODE 1: qkv scatter -> bf16 Qac/Qbd/K/Vt.
// EMODE 2: bf16 R scatter. EMODE 0: plain f32 out.
// ---------------------------------------------------------------------------
template<int AMODE, int EMODE, int ACT>
__global__ __launch_bounds__(256)
void gemm64(const float* __restrict__ A0, const float* __restrict__ A1,
            const float* __restrict__ B, const float* __restrict__ bias,
            void* __restrict__ O0, void* __restrict__ O1,
            void* __restrict__ O2, void* __restrict__ O3,
            const float* __restrict__ rwb, const float* __restrict__ rrb,
            int M, int N, int K)
{
    __shared__ float As[16][68];
    __shared__ float Bs[16][68];

    const int tid = threadIdx.x;
    const int m0 = blockIdx.x * 64;
    const int n0 = blockIdx.y * 64;
    const int tm = ((tid >> 4) & 15) << 2;
    const int tn = (tid & 15) << 2;
    const int sm = tid >> 2;
    const int sk = (tid & 3) << 2;

    float acc[4][4];
#pragma unroll
    for (int i2 = 0; i2 < 4; ++i2)
#pragma unroll
        for (int j2 = 0; j2 < 4; ++j2) acc[i2][j2] = 0.f;

    const int arow = m0 + sm;
    const float* aptr;
    if (AMODE == 0) {
        aptr = A0 + (size_t)arow * K + sk;
    } else {
        aptr = (arow < KLEN) ? (A0 + (size_t)arow * K + sk)
                             : (A1 + (size_t)(arow - KLEN) * K + sk);
    }
    const float* bptr = B + (size_t)(n0 + sm) * K + sk;

    for (int k0 = 0; k0 < K; k0 += 16) {
        float4 av = *(const float4*)(aptr + k0);
        float4 bv = *(const float4*)(bptr + k0);
        __syncthreads();
        As[sk + 0][sm] = av.x; As[sk + 1][sm] = av.y;
        As[sk + 2][sm] = av.z; As[sk + 3][sm] = av.w;
        Bs[sk + 0][sm] = bv.x; Bs[sk + 1][sm] = bv.y;
        Bs[sk + 2][sm] = bv.z; Bs[sk + 3][sm] = bv.w;
        __syncthreads();
#pragma unroll
        for (int kk = 0; kk < 16; ++kk) {
            float4 a4 = *(const float4*)&As[kk][tm];
            float4 b4 = *(const float4*)&Bs[kk][tn];
            float aa[4] = {a4.x, a4.y, a4.z, a4.w};
            float bb2[4] = {b4.x, b4.y, b4.z, b4.w};
#pragma unroll
            for (int i2 = 0; i2 < 4; ++i2)
#pragma unroll
                for (int j2 = 0; j2 < 4; ++j2)
                    acc[i2][j2] = fmaf(aa[i2], bb2[j2], acc[i2][j2]);
        }
    }

#pragma unroll
    for (int i2 = 0; i2 < 4; ++i2) {
        const int m = m0 + tm + i2;
#pragma unroll
        for (int j2 = 0; j2 < 4; ++j2) {
            const int n = n0 + tn + j2;
            float v = acc[i2][j2];
            if (EMODE == 0) {
                if (bias) v += bias[n];
                if (ACT == 1) v = fmaxf(v, 0.f);
                ((float*)O0)[(size_t)m * N + n] = v;
            } else if (EMODE == 1) {
                const int j = m >> 1, b = m & 1;
                const int part = n >> 10, hh = (n >> 6) & 15, d = n & 63;
                if (part == 0) {
                    if (j >= MLEN) {
                        const int qi = j - MLEN;
                        const size_t qidx = (((size_t)(b * NH + hh)) * QLEN + qi) * DH + d;
                        ((ushort_t*)O0)[qidx] = f2bf(v + rwb[hh * DH + d]);  // Qac
                        ((ushort_t*)O1)[qidx] = f2bf(v + rrb[hh * DH + d]);  // Qbd
                    }
                } else if (part == 1) {
                    ((ushort_t*)O2)[(((size_t)(b * NH + hh)) * KLEN + j) * DH + d] = f2bf(v);  // K
                } else {
                    ((ushort_t*)O3)[(((size_t)(b * NH + hh)) * DH + d) * KLEN + j] = f2bf(v);  // V^T
                }
            } else {  // EMODE 2: R
                const int hh = n >> 6, d = n & 63;
                ((ushort_t*)O0)[(((size_t)hh) * KLEN + m) * DH + d] = f2bf(v);
            }
        }
    }
}

// ---------------------------------------------------------------------------
// MFMA flash attention with TransformerXL rel-shift.
// Block = 4 waves = 64-row Q-tile of one (b,h). Wave w owns rows [w*16,w*16+16).
// score(i,j) = (Qac[i]·K[j] + Qbd[i]·R[j+QLEN-1-i]) * scale, valid j <= i+MLEN.
// BD computed as plain MFMA vs a sliding 128-row R window (ring buffer in LDS;
// only 64 new rows staged per chunk); AC added at shifted col jj+15-row.
// Softmax lane layout == PV A-fragment layout, so P stays in registers.
// ---------------------------------------------------------------------------
__global__ __launch_bounds__(256)
void attn_mfma(const ushort_t* __restrict__ Qac, const ushort_t* __restrict__ Qbd,
               const ushort_t* __restrict__ Kb, const ushort_t* __restrict__ Vt,
               const ushort_t* __restrict__ Rb, float* __restrict__ AV)
{
    __shared__ ushort_t Kt[64][72];    // K chunk [j][d], stride 72 -> clean quads
    __shared__ ushort_t Rt[128][72];   // R ring  [g&127][d]
    __shared__ ushort_t Vl[64][72];    // V^T chunk [d][j]
    __shared__ float    Bw[4][16][84]; // per-wave shifted score strip

    const int tid  = threadIdx.x;
    const int lane = tid & 63;
    const int w    = tid >> 6;
    const int lr   = lane & 15;
    const int quad = lane >> 4;
    const int bx   = blockIdx.x;
    const int i0   = bx << 6;
    const int bh   = blockIdx.y;
    const int h    = bh & 15;
    const int b    = bh >> 4;

    // Q fragments (A-operand layout: row=lane&15, k=quad*8+t per 32-k half)
    short8 qaf[2], qbf[2];
    {
        const size_t rowoff = ((size_t)bh * QLEN + i0 + w * 16 + lr) * DH;
#pragma unroll
        for (int kt = 0; kt < 2; ++kt) {
            qaf[kt] = *(const short8*)(Qac + rowoff + kt * 32 + quad * 8);
            qbf[kt] = *(const short8*)(Qbd + rowoff + kt * 32 + quad * 8);
        }
    }

    f32x4 O[4];
#pragma unroll
    for (int nt = 0; nt < 4; ++nt) O[nt] = (f32x4){0.f, 0.f, 0.f, 0.f};
    float m_run = -3.4e38f, l_run = 0.f;

    const int nc  = bx + 17;
    const int stw = 3 - w;                 // wave's first window col-tile
    const ushort_t* Kh = Kb + (size_t)bh * KLEN * DH;
    const ushort_t* Vh = Vt + (size_t)bh * DH * KLEN;
    const ushort_t* Rh = Rb + (size_t)h * KLEN * DH;

    for (int c = 0; c < nc; ++c) {
        const int j0 = c << 6;
        const int wb = 960 - i0 + j0;      // window base (global R row of wr=0)
        __syncthreads();                   // prior chunk's LDS reads done
        // stage K chunk
#pragma unroll
        for (int t = 0; t < 2; ++t) {
            int f = tid + (t << 8);
            int row = f >> 3, c8 = (f & 7) << 3;
            *(int4*)&Kt[row][c8] = *(const int4*)(Kh + (size_t)(j0 + row) * DH + c8);
        }
        // stage V^T chunk
#pragma unroll
        for (int t = 0; t < 2; ++t) {
            int f = tid + (t << 8);
            int d = f >> 3, c8 = (f & 7) << 3;
            *(int4*)&Vl[d][c8] = *(const int4*)(Vh + (size_t)d * KLEN + j0 + c8);
        }
        // stage R window (ring): chunk 0 loads 128 rows, later chunks 64 new
        {
            const int npass = (c == 0) ? 4 : 2;
            const int gb    = (c == 0) ? wb : wb + 64;
            for (int t = 0; t < npass; ++t) {
                int f = tid + (t << 8);
                int rl2 = f >> 3, c8 = (f & 7) << 3;
                int g = gb + rl2;
                int gc = g > (KLEN - 1) ? (KLEN - 1) : g;  // clamped rows feed only masked cells
                *(int4*)&Rt[g & 127][c8] = *(const int4*)(Rh + (size_t)gc * DH + c8);
            }
        }
        __syncthreads();

        // BD: 5 window col-tiles -> Bw[w][row][cb], cb = wr - stw*16
#pragma unroll
        for (int ctl = 0; ctl < 5; ++ctl) {
            const int wr = (stw + ctl) * 16 + lr;
            const int ring = (wb + wr) & 127;
            f32x4 z = (f32x4){0.f, 0.f, 0.f, 0.f};
#pragma unroll
            for (int kt = 0; kt < 2; ++kt) {
                short8 rb2 = *(const short8*)&Rt[ring][kt * 32 + quad * 8];
                z = __builtin_amdgcn_mfma_f32_16x16x32_bf16(qbf[kt], rb2, z, 0, 0, 0);
            }
#pragma unroll
            for (int rg = 0; rg < 4; ++rg)
                Bw[w][quad * 4 + rg][ctl * 16 + lr] = z[rg];
        }
        // AC: add at shifted position cb = jj + 15 - row
#pragma unroll
        for (int ct = 0; ct < 4; ++ct) {
            f32x4 z = (f32x4){0.f, 0.f, 0.f, 0.f};
#pragma unroll
            for (int kt = 0; kt < 2; ++kt) {
                short8 kb2 = *(const short8*)&Kt[ct * 16 + lr][kt * 32 + quad * 8];
                z = __builtin_amdgcn_mfma_f32_16x16x32_bf16(qaf[kt], kb2, z, 0, 0, 0);
            }
#pragma unroll
            for (int rg = 0; rg < 4; ++rg) {
                const int rrow = quad * 4 + rg;
                Bw[w][rrow][ct * 16 + lr + 15 - rrow] += z[rg];
            }
        }

        // online softmax; lane covers jj = kt*32 + quad*8 + t  (== PV A-frag)
        const int lim = i0 + w * 16 + lr + 1024 - j0;  // jj <= lim valid
        float pv[16];
        float mx = -3.4e38f;
#pragma unroll
        for (int kt = 0; kt < 2; ++kt)
#pragma unroll
            for (int t = 0; t < 8; ++t) {
                const int jj = kt * 32 + quad * 8 + t;
                float s = Bw[w][lr][jj + 15 - lr] * 0.125f;
                s = (jj > lim) ? -3.4e38f : s;
                pv[kt * 8 + t] = s;
                mx = fmaxf(mx, s);
            }
        mx = fmaxf(mx, __shfl_xor(mx, 16, 64));
        mx = fmaxf(mx, __shfl_xor(mx, 32, 64));
        const float m_new = fmaxf(m_run, mx);
        float ps = 0.f;
        short8 pf[2];
#pragma unroll
        for (int kt = 0; kt < 2; ++kt)
#pragma unroll
            for (int t = 0; t < 8; ++t) {
                const float e = __expf(pv[kt * 8 + t] - m_new);
                ps += e;
                pf[kt][t] = (short)f2bf(e);
            }
        ps += __shfl_xor(ps, 16, 64);
        ps += __shfl_xor(ps, 32, 64);
        const float alpha = __expf(m_run - m_new);
        m_run = m_new;
        l_run = l_run * alpha + ps;

        // rescale O (C-layout rows = quad*4+rg; alpha lives at lane row&15)
        float ar[4];
#pragma unroll
        for (int rg = 0; rg < 4; ++rg)
            ar[rg] = __shfl(alpha, quad * 4 + rg, 64);
#pragma unroll
        for (int nt = 0; nt < 4; ++nt) {
            O[nt][0] *= ar[0]; O[nt][1] *= ar[1];
            O[nt][2] *= ar[2]; O[nt][3] *= ar[3];
        }
        // PV: O += P @ V  (B-operand from V^T tile, n = d)
#pragma unroll
        for (int kt = 0; kt < 2; ++kt)
#pragma unroll
            for (int nt = 0; nt < 4; ++nt) {
                short8 vb = *(const short8*)&Vl[nt * 16 + lr][kt * 32 + quad * 8];
                O[nt] = __builtin_amdgcn_mfma_f32_16x16x32_bf16(pf[kt], vb, O[nt], 0, 0, 0);
            }
    }

    // epilogue: divide by l, write attn_vec rows (i*BSZ+b) x (h*64+d)
    float rlv[4];
#pragma unroll
    for (int rg = 0; rg < 4; ++rg)
        rlv[rg] = 1.f / __shfl(l_run, quad * 4 + rg, 64);
#pragma unroll
    for (int nt = 0; nt < 4; ++nt)
#pragma unroll
        for (int rg = 0; rg < 4; ++rg) {
            const int i = i0 + w * 16 + quad * 4 + rg;
            AV[((size_t)i * BSZc + b) * DM + h * DH + nt * 16 + lr] = O[nt][rg] * rlv[rg];
        }
}

// ---------------------------------------------------------------------------
__global__ __launch_bounds__(256)
void add_ln(const float* __restrict__ X, const float* __restrict__ Y,
            const float* __restrict__ gg, const float* __restrict__ bb,
            float* __restrict__ out)
{
    const int row  = blockIdx.x;
    const int tid  = threadIdx.x;
    const int lane = tid & 63;
    const int w    = tid >> 6;
    __shared__ float ssum[4], ssq[4];

    const float4 xv = ((const float4*)(X + (size_t)row * DM))[tid];
    const float4 yv = ((const float4*)(Y + (size_t)row * DM))[tid];
    const float v0 = xv.x + yv.x, v1 = xv.y + yv.y;
    const float v2 = xv.z + yv.z, v3 = xv.w + yv.w;
    float s = v0 + v1 + v2 + v3;
    float q = v0 * v0 + v1 * v1 + v2 * v2 + v3 * v3;
#pragma unroll
    for (int off = 32; off > 0; off >>= 1) {
        s += __shfl_xor(s, off, 64);
        q += __shfl_xor(q, off, 64);
    }
    if (lane == 0) { ssum[w] = s; ssq[w] = q; }
    __syncthreads();
    s = ssum[0] + ssum[1] + ssum[2] + ssum[3];
    q = ssq[0] + ssq[1] + ssq[2] + ssq[3];
    const float mean = s * (1.f / DM);
    const float var  = q * (1.f / DM) - mean * mean;
    const float rs   = rsqrtf(var + 1e-5f);
    const float4 g4 = ((const float4*)gg)[tid];
    const float4 b4 = ((const float4*)bb)[tid];
    float4 ov;
    ov.x = (v0 - mean) * rs * g4.x + b4.x;
    ov.y = (v1 - mean) * rs * g4.y + b4.y;
    ov.z = (v2 - mean) * rs * g4.z + b4.z;
    ov.w = (v3 - mean) * rs * g4.w + b4.w;
    ((float4*)(out + (size_t)row * DM))[tid] = ov;
}

// ---------------------------------------------------------------------------
extern "C" void kernel_launch(void* const* d_in, const int* in_sizes, int n_in,
                              void* d_out, int out_size, void* d_ws, size_t ws_size,
                              hipStream_t stream)
{
    (void)in_sizes; (void)n_in; (void)out_size; (void)ws_size;
    const float* w      = (const float*)d_in[0];
    const float* r      = (const float*)d_in[1];
    const float* mems   = (const float*)d_in[2];
    // d_in[3] attn_mask: deterministic (j > i + MLEN), applied analytically
    const float* qkv_w  = (const float*)d_in[4];
    const float* rnet_w = (const float*)d_in[5];
    const float* o_w    = (const float*)d_in[6];
    const float* r_r_b  = (const float*)d_in[7];
    const float* r_w_b  = (const float*)d_in[8];
    const float* ln1g   = (const float*)d_in[9];
    const float* ln1b   = (const float*)d_in[10];
    const float* ffw1   = (const float*)d_in[11];
    const float* ffb1   = (const float*)d_in[12];
    const float* ffw2   = (const float*)d_in[13];
    const float* ffb2   = (const float*)d_in[14];
    const float* ln2g   = (const float*)d_in[15];
    const float* ln2b   = (const float*)d_in[16];
    float* out = (float*)d_out;

    char* wsb = (char*)d_ws;
    const size_t MB = 1024 * 1024;
    // phase 1 (attention inputs, bf16)
    ushort_t* Qac_bf = (ushort_t*)(wsb + 0 * MB);   // [bh][1024][64]   4 MB
    ushort_t* Qbd_bf = (ushort_t*)(wsb + 4 * MB);   //                  4 MB
    ushort_t* K_bf   = (ushort_t*)(wsb + 8 * MB);   // [bh][2048][64]   8 MB
    ushort_t* Vt_bf  = (ushort_t*)(wsb + 16 * MB);  // [bh][64][2048]   8 MB
    ushort_t* R_bf   = (ushort_t*)(wsb + 24 * MB);  // [h][2048][64]    4 MB
    float*    AVec   = (float*)(wsb + 56 * MB);     // (i,b) x 1024     8 MB
    // phase 2 (attention buffers dead)
    float* AOut = (float*)(wsb + 0 * MB);           // 8 MB
    float* Hbuf = (float*)(wsb + 8 * MB);           // 8 MB
    float* FF   = (float*)(wsb + 16 * MB);          // 32 MB
    float* Core = (float*)(wsb + 48 * MB);          // 8 MB
    // total 64 MB

    dim3 blk(256);

    // 1. QKV projection -> bf16 Qac/Qbd (bias added), K, V^T
    gemm64<1, 1, 0><<<dim3(64, 48), blk, 0, stream>>>(
        mems, w, qkv_w, nullptr, Qac_bf, Qbd_bf, K_bf, Vt_bf, r_w_b, r_r_b,
        2 * KLEN, 3 * DM, DM);

    // 2. r_head_k -> bf16 R[h][klen][dh]
    gemm64<0, 2, 0><<<dim3(32, 16), blk, 0, stream>>>(
        r, nullptr, rnet_w, nullptr, R_bf, nullptr, nullptr, nullptr,
        nullptr, nullptr, KLEN, DM, DM);

    // 3. MFMA flash attention
    attn_mfma<<<dim3(QLEN / 64, BSZc * NH), blk, 0, stream>>>(
        Qac_bf, Qbd_bf, K_bf, Vt_bf, R_bf, AVec);

    // 4. output projection
    gemm64<0, 0, 0><<<dim3(32, 16), blk, 0, stream>>>(
        AVec, nullptr, o_w, nullptr, AOut, nullptr, nullptr, nullptr,
        nullptr, nullptr, 2 * QLEN, DM, DM);

    // 5. h = LN(w + attn_out)
    add_ln<<<dim3(2 * QLEN), blk, 0, stream>>>(w, AOut, ln1g, ln1b, Hbuf);

    // 6. FF1: relu(h @ ff_w1^T + b1)
    gemm64<0, 0, 1><<<dim3(32, 64), blk, 0, stream>>>(
        Hbuf, nullptr, ffw1, ffb1, FF, nullptr, nullptr, nullptr,
        nullptr, nullptr, 2 * QLEN, DI, DM);

    // 7. FF2
    gemm64<0, 0, 0><<<dim3(32, 16), blk, 0, stream>>>(
        FF, nullptr, ffw2, ffb2, Core, nullptr, nullptr, nullptr,
        nullptr, nullptr, 2 * QLEN, DM, DI);

    // 8. out = LN(h + core)
    add_ln<<<dim3(2 * QLEN), blk, 0, stream>>>(Hbuf, Core, ln2g, ln2b, out);
}

// Round 4
// 461.380 us; speedup vs baseline: 4.7518x; 2.7058x over previous
//
#include <hip/hip_runtime.h>
#include <math.h>

#define QLEN 1024
#define MLEN 1024
#define KLEN 2048
#define BSZc 2
#define NH 16
#define DH 64
#define DM 1024
#define DI 4096

typedef unsigned short ushort_t;
typedef __attribute__((ext_vector_type(8))) short short8;
typedef __attribute__((ext_vector_type(4))) float f32x4;

__device__ __forceinline__ ushort_t f2bf(float x) {
    unsigned int u = __float_as_uint(x);
    unsigned int r = (u + 0x7FFFu + ((u >> 16) & 1u)) >> 16;
    return (ushort_t)r;
}

__device__ __forceinline__ void gload_lds16(const ushort_t* g, ushort_t* l) {
    __builtin_amdgcn_global_load_lds(
        (const __attribute__((address_space(1))) unsigned int*)g,
        (__attribute__((address_space(3))) unsigned int*)l,
        16, 0, 0);
}

// ---------------------------------------------------------------------------
// f32 -> bf16 cast, 8 elems/thread
// ---------------------------------------------------------------------------
__global__ __launch_bounds__(256)
void castbf(const float* __restrict__ s, ushort_t* __restrict__ d, int n)
{
    const int i = (blockIdx.x * 256 + threadIdx.x) * 8;
    if (i >= n) return;
    const float4 a = *(const float4*)(s + i);
    const float4 b = *(const float4*)(s + i + 4);
    short8 o;
    o[0] = (short)f2bf(a.x); o[1] = (short)f2bf(a.y);
    o[2] = (short)f2bf(a.z); o[3] = (short)f2bf(a.w);
    o[4] = (short)f2bf(b.x); o[5] = (short)f2bf(b.y);
    o[6] = (short)f2bf(b.z); o[7] = (short)f2bf(b.w);
    *(short8*)(d + i) = o;
}

// ---------------------------------------------------------------------------
// bf16 MFMA GEMM (m97 structure): C = A @ B^T. A: MxK, B: NxK, both rowmajor
// bf16, K%32==0, M%128==0, N%BN==0. Block = 4 waves, 128 x BN tile, BK=32,
// global_load_lds width-16 staging, 16x16x32 MFMA.
// EMODE 0: f32 out (+bias). EMODE 1: QKV scatter -> bf16 Qac/Qbd/K/Vt.
// EMODE 2: bf16 R scatter. EMODE 3: bf16 out (+bias, +relu if ACT).
// ---------------------------------------------------------------------------
template<int EMODE, int ACT, int BN>
__global__ __launch_bounds__(256)
void gemm_mfma(const ushort_t* __restrict__ A, const ushort_t* __restrict__ B,
               const float* __restrict__ bias,
               void* __restrict__ O0, void* __restrict__ O1,
               void* __restrict__ O2, void* __restrict__ O3,
               const float* __restrict__ rwb, const float* __restrict__ rrb,
               int M, int N, int K)
{
    constexpr int JT = BN / 32;            // n-tiles per wave (2 or 4)
    __shared__ ushort_t At[128 * 32];
    __shared__ ushort_t Bt[BN * 32];

    const int tid  = threadIdx.x;
    const int lane = tid & 63;
    const int w    = tid >> 6;
    const int lr   = lane & 15;
    const int quad = lane >> 4;
    const int m0   = blockIdx.x * 128;
    const int n0   = blockIdx.y * BN;
    const int wm0  = (w >> 1) * 64;        // wave row offset in C-tile
    const int wn0  = (w & 1) * (BN / 2);   // wave col offset

    f32x4 acc[4][JT];
#pragma unroll
    for (int it = 0; it < 4; ++it)
#pragma unroll
        for (int jt = 0; jt < JT; ++jt) acc[it][jt] = (f32x4){0.f, 0.f, 0.f, 0.f};

    const int srow = lane >> 2;            // 0..15
    const int scol = (lane & 3) << 3;      // 0,8,16,24
    const ushort_t* Ag = A + (size_t)(m0 + w * 32 + srow) * K + scol;
    ushort_t* lA0 = At + (w * 32) * 32;
    ushort_t* lA1 = At + (w * 32 + 16) * 32;
    const ushort_t* Bg;
    ushort_t *lB0, *lB1 = nullptr;
    if (BN == 128) {
        Bg  = B + (size_t)(n0 + w * 32 + srow) * K + scol;
        lB0 = Bt + (w * 32) * 32;
        lB1 = Bt + (w * 32 + 16) * 32;
    } else {  // BN == 64
        Bg  = B + (size_t)(n0 + w * 16 + srow) * K + scol;
        lB0 = Bt + (w * 16) * 32;
    }

    const ushort_t* Ato = At + (wm0 + lr) * 32 + quad * 8;
    const ushort_t* Bto = Bt + (wn0 + lr) * 32 + quad * 8;

    for (int k0 = 0; k0 < K; k0 += 32) {
        __syncthreads();                   // prior iter's frag reads done
        gload_lds16(Ag + k0, lA0);
        gload_lds16(Ag + (size_t)16 * K + k0, lA1);
        gload_lds16(Bg + k0, lB0);
        if (BN == 128) gload_lds16(Bg + (size_t)16 * K + k0, lB1);
        __syncthreads();

        short8 af[4], bf[JT];
#pragma unroll
        for (int it = 0; it < 4; ++it)
            af[it] = *(const short8*)(Ato + it * 16 * 32);
#pragma unroll
        for (int jt = 0; jt < JT; ++jt)
            bf[jt] = *(const short8*)(Bto + jt * 16 * 32);
#pragma unroll
        for (int it = 0; it < 4; ++it)
#pragma unroll
            for (int jt = 0; jt < JT; ++jt)
                acc[it][jt] = __builtin_amdgcn_mfma_f32_16x16x32_bf16(
                    af[it], bf[jt], acc[it][jt], 0, 0, 0);
    }

#pragma unroll
    for (int it = 0; it < 4; ++it)
#pragma unroll
        for (int jt = 0; jt < JT; ++jt)
#pragma unroll
            for (int rg = 0; rg < 4; ++rg) {
                const int m = m0 + wm0 + it * 16 + quad * 4 + rg;
                const int n = n0 + wn0 + jt * 16 + lr;
                float v = acc[it][jt][rg];
                if (EMODE == 0) {
                    if (bias) v += bias[n];
                    ((float*)O0)[(size_t)m * N + n] = v;
                } else if (EMODE == 1) {
                    const int j = m >> 1, b = m & 1;
                    const int part = n >> 10, hh = (n >> 6) & 15, d = n & 63;
                    if (part == 0) {
                        if (j >= MLEN) {
                            const int qi = j - MLEN;
                            const size_t qidx = (((size_t)(b * NH + hh)) * QLEN + qi) * DH + d;
                            ((ushort_t*)O0)[qidx] = f2bf(v + rwb[hh * DH + d]);
                            ((ushort_t*)O1)[qidx] = f2bf(v + rrb[hh * DH + d]);
                        }
                    } else if (part == 1) {
                        ((ushort_t*)O2)[(((size_t)(b * NH + hh)) * KLEN + j) * DH + d] = f2bf(v);
                    } else {
                        ((ushort_t*)O3)[(((size_t)(b * NH + hh)) * DH + d) * KLEN + j] = f2bf(v);
                    }
                } else if (EMODE == 2) {
                    const int hh = n >> 6, d = n & 63;
                    ((ushort_t*)O0)[(((size_t)hh) * KLEN + m) * DH + d] = f2bf(v);
                } else {  // EMODE 3
                    v += bias[n];
                    if (ACT == 1) v = fmaxf(v, 0.f);
                    ((ushort_t*)O0)[(size_t)m * N + n] = f2bf(v);
                }
            }
}

// ---------------------------------------------------------------------------
// MFMA flash attention with TransformerXL rel-shift.
// ---------------------------------------------------------------------------
__global__ __launch_bounds__(256)
void attn_mfma(const ushort_t* __restrict__ Qac, const ushort_t* __restrict__ Qbd,
               const ushort_t* __restrict__ Kb, const ushort_t* __restrict__ Vt,
               const ushort_t* __restrict__ Rb, ushort_t* __restrict__ AV)
{
    __shared__ ushort_t Kt[64][72];
    __shared__ ushort_t Rt[128][72];
    __shared__ ushort_t Vl[64][72];
    __shared__ float    Bw[4][16][84];

    const int tid  = threadIdx.x;
    const int lane = tid & 63;
    const int w    = tid >> 6;
    const int lr   = lane & 15;
    const int quad = lane >> 4;
    const int bx   = blockIdx.x;
    const int i0   = bx << 6;
    const int bh   = blockIdx.y;
    const int h    = bh & 15;
    const int b    = bh >> 4;

    short8 qaf[2], qbf[2];
    {
        const size_t rowoff = ((size_t)bh * QLEN + i0 + w * 16 + lr) * DH;
#pragma unroll
        for (int kt = 0; kt < 2; ++kt) {
            qaf[kt] = *(const short8*)(Qac + rowoff + kt * 32 + quad * 8);
            qbf[kt] = *(const short8*)(Qbd + rowoff + kt * 32 + quad * 8);
        }
    }

    f32x4 O[4];
#pragma unroll
    for (int nt = 0; nt < 4; ++nt) O[nt] = (f32x4){0.f, 0.f, 0.f, 0.f};
    float m_run = -3.4e38f, l_run = 0.f;

    const int nc  = bx + 17;
    const int stw = 3 - w;
    const ushort_t* Kh = Kb + (size_t)bh * KLEN * DH;
    const ushort_t* Vh = Vt + (size_t)bh * DH * KLEN;
    const ushort_t* Rh = Rb + (size_t)h * KLEN * DH;

    for (int c = 0; c < nc; ++c) {
        const int j0 = c << 6;
        const int wb = 960 - i0 + j0;
        __syncthreads();
#pragma unroll
        for (int t = 0; t < 2; ++t) {
            int f = tid + (t << 8);
            int row = f >> 3, c8 = (f & 7) << 3;
            *(int4*)&Kt[row][c8] = *(const int4*)(Kh + (size_t)(j0 + row) * DH + c8);
        }
#pragma unroll
        for (int t = 0; t < 2; ++t) {
            int f = tid + (t << 8);
            int d = f >> 3, c8 = (f & 7) << 3;
            *(int4*)&Vl[d][c8] = *(const int4*)(Vh + (size_t)d * KLEN + j0 + c8);
        }
        {
            const int npass = (c == 0) ? 4 : 2;
            const int gb    = (c == 0) ? wb : wb + 64;
            for (int t = 0; t < npass; ++t) {
                int f = tid + (t << 8);
                int rl2 = f >> 3, c8 = (f & 7) << 3;
                int g = gb + rl2;
                int gc = g > (KLEN - 1) ? (KLEN - 1) : g;
                *(int4*)&Rt[g & 127][c8] = *(const int4*)(Rh + (size_t)gc * DH + c8);
            }
        }
        __syncthreads();

#pragma unroll
        for (int ctl = 0; ctl < 5; ++ctl) {
            const int wr = (stw + ctl) * 16 + lr;
            const int ring = (wb + wr) & 127;
            f32x4 z = (f32x4){0.f, 0.f, 0.f, 0.f};
#pragma unroll
            for (int kt = 0; kt < 2; ++kt) {
                short8 rb2 = *(const short8*)&Rt[ring][kt * 32 + quad * 8];
                z = __builtin_amdgcn_mfma_f32_16x16x32_bf16(qbf[kt], rb2, z, 0, 0, 0);
            }
#pragma unroll
            for (int rg = 0; rg < 4; ++rg)
                Bw[w][quad * 4 + rg][ctl * 16 + lr] = z[rg];
        }
#pragma unroll
        for (int ct = 0; ct < 4; ++ct) {
            f32x4 z = (f32x4){0.f, 0.f, 0.f, 0.f};
#pragma unroll
            for (int kt = 0; kt < 2; ++kt) {
                short8 kb2 = *(const short8*)&Kt[ct * 16 + lr][kt * 32 + quad * 8];
                z = __builtin_amdgcn_mfma_f32_16x16x32_bf16(qaf[kt], kb2, z, 0, 0, 0);
            }
#pragma unroll
            for (int rg = 0; rg < 4; ++rg) {
                const int rrow = quad * 4 + rg;
                Bw[w][rrow][ct * 16 + lr + 15 - rrow] += z[rg];
            }
        }

        const int lim = i0 + w * 16 + lr + 1024 - j0;
        float pv[16];
        float mx = -3.4e38f;
#pragma unroll
        for (int kt = 0; kt < 2; ++kt)
#pragma unroll
            for (int t = 0; t < 8; ++t) {
                const int jj = kt * 32 + quad * 8 + t;
                float s = Bw[w][lr][jj + 15 - lr] * 0.125f;
                s = (jj > lim) ? -3.4e38f : s;
                pv[kt * 8 + t] = s;
                mx = fmaxf(mx, s);
            }
        mx = fmaxf(mx, __shfl_xor(mx, 16, 64));
        mx = fmaxf(mx, __shfl_xor(mx, 32, 64));
        const float m_new = fmaxf(m_run, mx);
        float ps = 0.f;
        short8 pf[2];
#pragma unroll
        for (int kt = 0; kt < 2; ++kt)
#pragma unroll
            for (int t = 0; t < 8; ++t) {
                const float e = __expf(pv[kt * 8 + t] - m_new);
                ps += e;
                pf[kt][t] = (short)f2bf(e);
            }
        ps += __shfl_xor(ps, 16, 64);
        ps += __shfl_xor(ps, 32, 64);
        const float alpha = __expf(m_run - m_new);
        m_run = m_new;
        l_run = l_run * alpha + ps;

        float ar[4];
#pragma unroll
        for (int rg = 0; rg < 4; ++rg)
            ar[rg] = __shfl(alpha, quad * 4 + rg, 64);
#pragma unroll
        for (int nt = 0; nt < 4; ++nt) {
            O[nt][0] *= ar[0]; O[nt][1] *= ar[1];
            O[nt][2] *= ar[2]; O[nt][3] *= ar[3];
        }
#pragma unroll
        for (int kt = 0; kt < 2; ++kt)
#pragma unroll
            for (int nt = 0; nt < 4; ++nt) {
                short8 vb = *(const short8*)&Vl[nt * 16 + lr][kt * 32 + quad * 8];
                O[nt] = __builtin_amdgcn_mfma_f32_16x16x32_bf16(pf[kt], vb, O[nt], 0, 0, 0);
            }
    }

    float rlv[4];
#pragma unroll
    for (int rg = 0; rg < 4; ++rg)
        rlv[rg] = 1.f / __shfl(l_run, quad * 4 + rg, 64);
#pragma unroll
    for (int nt = 0; nt < 4; ++nt)
#pragma unroll
        for (int rg = 0; rg < 4; ++rg) {
            const int i = i0 + w * 16 + quad * 4 + rg;
            AV[((size_t)i * BSZc + b) * DM + h * DH + nt * 16 + lr] = f2bf(O[nt][rg] * rlv[rg]);
        }
}

// ---------------------------------------------------------------------------
// out = LayerNorm(X + Y); optional bf16 secondary output
// ---------------------------------------------------------------------------
__global__ __launch_bounds__(256)
void add_ln(const float* __restrict__ X, const float* __restrict__ Y,
            const float* __restrict__ gg, const float* __restrict__ bb,
            float* __restrict__ out, ushort_t* __restrict__ outb)
{
    const int row  = blockIdx.x;
    const int tid  = threadIdx.x;
    const int lane = tid & 63;
    const int w    = tid >> 6;
    __shared__ float ssum[4], ssq[4];

    const float4 xv = ((const float4*)(X + (size_t)row * DM))[tid];
    const float4 yv = ((const float4*)(Y + (size_t)row * DM))[tid];
    const float v0 = xv.x + yv.x, v1 = xv.y + yv.y;
    const float v2 = xv.z + yv.z, v3 = xv.w + yv.w;
    float s = v0 + v1 + v2 + v3;
    float q = v0 * v0 + v1 * v1 + v2 * v2 + v3 * v3;
#pragma unroll
    for (int off = 32; off > 0; off >>= 1) {
        s += __shfl_xor(s, off, 64);
        q += __shfl_xor(q, off, 64);
    }
    if (lane == 0) { ssum[w] = s; ssq[w] = q; }
    __syncthreads();
    s = ssum[0] + ssum[1] + ssum[2] + ssum[3];
    q = ssq[0] + ssq[1] + ssq[2] + ssq[3];
    const float mean = s * (1.f / DM);
    const float var  = q * (1.f / DM) - mean * mean;
    const float rs   = rsqrtf(var + 1e-5f);
    const float4 g4 = ((const float4*)gg)[tid];
    const float4 b4 = ((const float4*)bb)[tid];
    float4 ov;
    ov.x = (v0 - mean) * rs * g4.x + b4.x;
    ov.y = (v1 - mean) * rs * g4.y + b4.y;
    ov.z = (v2 - mean) * rs * g4.z + b4.z;
    ov.w = (v3 - mean) * rs * g4.w + b4.w;
    ((float4*)(out + (size_t)row * DM))[tid] = ov;
    if (outb) {
        ushort_t* p = outb + (size_t)row * DM + tid * 4;
        p[0] = f2bf(ov.x); p[1] = f2bf(ov.y);
        p[2] = f2bf(ov.z); p[3] = f2bf(ov.w);
    }
}

// ---------------------------------------------------------------------------
extern "C" void kernel_launch(void* const* d_in, const int* in_sizes, int n_in,
                              void* d_out, int out_size, void* d_ws, size_t ws_size,
                              hipStream_t stream)
{
    (void)in_sizes; (void)n_in; (void)out_size; (void)ws_size;
    const float* w      = (const float*)d_in[0];
    const float* r      = (const float*)d_in[1];
    const float* mems   = (const float*)d_in[2];
    // d_in[3] attn_mask: deterministic (j > i + MLEN), applied analytically
    const float* qkv_w  = (const float*)d_in[4];
    const float* rnet_w = (const float*)d_in[5];
    const float* o_w    = (const float*)d_in[6];
    const float* r_r_b  = (const float*)d_in[7];
    const float* r_w_b  = (const float*)d_in[8];
    const float* ln1g   = (const float*)d_in[9];
    const float* ln1b   = (const float*)d_in[10];
    const float* ffw1   = (const float*)d_in[11];
    const float* ffb1   = (const float*)d_in[12];
    const float* ffw2   = (const float*)d_in[13];
    const float* ffb2   = (const float*)d_in[14];
    const float* ln2g   = (const float*)d_in[15];
    const float* ln2b   = (const float*)d_in[16];
    float* out = (float*)d_out;

    char* wsb = (char*)d_ws;
    const size_t MB = 1024 * 1024;
    // ---- workspace layout, live ranges verified against launch order ----
    // phase 1:
    ushort_t* W1    = (ushort_t*)(wsb + 0 * MB);   // qkv_w bf16   0-6   [dead after step 1]
    ushort_t* W2    = (ushort_t*)(wsb + 6 * MB);   // rnet_w bf16  6-8   [dead after step 2]
    ushort_t* Acat  = (ushort_t*)(wsb + 8 * MB);   // cat bf16     8-16  [dead after step 1]
    ushort_t* Rsrc  = (ushort_t*)(wsb + 16 * MB);  // r bf16       16-20 [dead after step 2]
    ushort_t* Qac   = (ushort_t*)(wsb + 20 * MB);  //              20-24 [dead after step 3]
    ushort_t* Qbd   = (ushort_t*)(wsb + 24 * MB);  //              24-28 [dead after step 3]
    ushort_t* Kbf   = (ushort_t*)(wsb + 28 * MB);  //              28-36 [dead after step 3]
    ushort_t* Vt    = (ushort_t*)(wsb + 36 * MB);  //              36-44 [dead after step 3]
    ushort_t* Rh    = (ushort_t*)(wsb + 44 * MB);  //              44-48 [dead after step 3]
    // phase 2 (each over fully-dead regions):
    ushort_t* AVec  = (ushort_t*)(wsb + 0 * MB);   // 0-4  (over W1)        live 3->4
    ushort_t* W3    = (ushort_t*)(wsb + 4 * MB);   // 4-6  (over W1)        live cast->4
    float*    AOut  = (float*)(wsb + 8 * MB);      // 8-16 (over Acat)      live 4->5
    float*    Hbuf  = (float*)(wsb + 16 * MB);     // 16-24 (Rsrc/Qac)      live 5->8
    ushort_t* Hbf   = (ushort_t*)(wsb + 24 * MB);  // 24-28 (Qbd)           live 5->6
    ushort_t* W4    = (ushort_t*)(wsb + 28 * MB);  // 28-36 (Kbf)           live cast->6
    ushort_t* FFbf  = (ushort_t*)(wsb + 36 * MB);  // 36-52 (Vt/Rh)         live 6->7
    ushort_t* W5    = (ushort_t*)(wsb + 52 * MB);  // 52-60 (virgin)        live cast->7
    float*    Core  = (float*)(wsb + 0 * MB);      // 0-8  (AVec/W3 dead)   live 7->8
    // peak 60 MB

    dim3 blk(256);

    // --- casts for phase 1 ---
    castbf<<<dim3(3145728 / 2048), blk, 0, stream>>>(qkv_w, W1, 3145728);
    castbf<<<dim3(1048576 / 2048), blk, 0, stream>>>(rnet_w, W2, 1048576);
    castbf<<<dim3(2097152 / 2048), blk, 0, stream>>>(mems, Acat, 2097152);
    castbf<<<dim3(2097152 / 2048), blk, 0, stream>>>(w, Acat + 2097152, 2097152);
    castbf<<<dim3(2097152 / 2048), blk, 0, stream>>>(r, Rsrc, 2097152);

    // 1. QKV projection -> Qac/Qbd (bias added), K, V^T  (bf16 MFMA)
    gemm_mfma<1, 0, 128><<<dim3(32, 24), blk, 0, stream>>>(
        Acat, W1, nullptr, Qac, Qbd, Kbf, Vt, r_w_b, r_r_b, 4096, 3072, 1024);

    // 2. r_head_k -> R[h][klen][dh]
    gemm_mfma<2, 0, 64><<<dim3(16, 16), blk, 0, stream>>>(
        Rsrc, W2, nullptr, Rh, nullptr, nullptr, nullptr, nullptr, nullptr,
        2048, 1024, 1024);

    // 3. MFMA flash attention -> bf16 attn_vec
    attn_mfma<<<dim3(QLEN / 64, BSZc * NH), blk, 0, stream>>>(
        Qac, Qbd, Kbf, Vt, Rh, AVec);

    // 4. output projection (f32 out)
    castbf<<<dim3(1048576 / 2048), blk, 0, stream>>>(o_w, W3, 1048576);
    gemm_mfma<0, 0, 64><<<dim3(16, 16), blk, 0, stream>>>(
        AVec, W3, nullptr, AOut, nullptr, nullptr, nullptr, nullptr, nullptr,
        2048, 1024, 1024);

    // 5. h = LN(w + attn_out)  (f32 + bf16 copies)
    add_ln<<<dim3(2 * QLEN), blk, 0, stream>>>(w, AOut, ln1g, ln1b, Hbuf, Hbf);

    // 6. FF1: relu(h @ ff_w1^T + b1) -> bf16
    castbf<<<dim3(4194304 / 2048), blk, 0, stream>>>(ffw1, W4, 4194304);
    gemm_mfma<3, 1, 128><<<dim3(16, 32), blk, 0, stream>>>(
        Hbf, W4, ffb1, FFbf, nullptr, nullptr, nullptr, nullptr, nullptr,
        2048, 4096, 1024);

    // 7. FF2 -> f32 Core
    castbf<<<dim3(4194304 / 2048), blk, 0, stream>>>(ffw2, W5, 4194304);
    gemm_mfma<0, 0, 64><<<dim3(16, 16), blk, 0, stream>>>(
        FFbf, W5, ffb2, Core, nullptr, nullptr, nullptr, nullptr, nullptr,
        2048, 1024, 4096);

    // 8. out = LN(h + core)
    add_ln<<<dim3(2 * QLEN), blk, 0, stream>>>(Hbuf, Core, ln2g, ln2b, out, nullptr);
}

// Round 5
// 460.015 us; speedup vs baseline: 4.7659x; 1.0030x over previous
//
#include <hip/hip_runtime.h>
#include <math.h>

#define QLEN 1024
#define MLEN 1024
#define KLEN 2048
#define BSZc 2
#define NH 16
#define DH 64
#define DM 1024
#define DI 4096

typedef unsigned short ushort_t;
typedef __attribute__((ext_vector_type(8))) short short8;
typedef __attribute__((ext_vector_type(4))) float f32x4;

__device__ __forceinline__ ushort_t f2bf(float x) {
    unsigned int u = __float_as_uint(x);
    unsigned int r = (u + 0x7FFFu + ((u >> 16) & 1u)) >> 16;
    return (ushort_t)r;
}
__device__ __forceinline__ float bf2f(ushort_t b) {
    return __uint_as_float(((unsigned int)b) << 16);
}

__device__ __forceinline__ void gload_lds16(const ushort_t* g, ushort_t* l) {
    __builtin_amdgcn_global_load_lds(
        (const __attribute__((address_space(1))) unsigned int*)g,
        (__attribute__((address_space(3))) unsigned int*)l,
        16, 0, 0);
}

// ---------------------------------------------------------------------------
// segmented f32 -> bf16 casts (one launch per phase)
// ---------------------------------------------------------------------------
__device__ __forceinline__ void cast8(const float* s, ushort_t* d, int g) {
    const float4 a = *(const float4*)(s + g * 8);
    const float4 b = *(const float4*)(s + g * 8 + 4);
    short8 o;
    o[0] = (short)f2bf(a.x); o[1] = (short)f2bf(a.y);
    o[2] = (short)f2bf(a.z); o[3] = (short)f2bf(a.w);
    o[4] = (short)f2bf(b.x); o[5] = (short)f2bf(b.y);
    o[6] = (short)f2bf(b.z); o[7] = (short)f2bf(b.w);
    *(short8*)(d + g * 8) = o;
}

__global__ __launch_bounds__(256)
void cast_phase1(const float* __restrict__ qkv_w, const float* __restrict__ rnet_w,
                 const float* __restrict__ mems, const float* __restrict__ w,
                 const float* __restrict__ r,
                 ushort_t* __restrict__ W1, ushort_t* __restrict__ W2,
                 ushort_t* __restrict__ Acat, ushort_t* __restrict__ Rsrc)
{
    int g = blockIdx.x * 256 + threadIdx.x;   // 8-elem group index
    if (g < 393216)            { cast8(qkv_w,  W1,              g); }
    else if (g < 524288)       { cast8(rnet_w, W2,              g - 393216); }
    else if (g < 786432)       { cast8(mems,   Acat,            g - 524288); }
    else if (g < 1048576)      { cast8(w,      Acat + 2097152,  g - 786432); }
    else if (g < 1310720)      { cast8(r,      Rsrc,            g - 1048576); }
}

__global__ __launch_bounds__(256)
void cast_phase2(const float* __restrict__ o_w, const float* __restrict__ ffw1,
                 const float* __restrict__ ffw2,
                 ushort_t* __restrict__ W3, ushort_t* __restrict__ W4,
                 ushort_t* __restrict__ W5)
{
    int g = blockIdx.x * 256 + threadIdx.x;
    if (g < 131072)            { cast8(o_w,  W3, g); }
    else if (g < 655360)       { cast8(ffw1, W4, g - 131072); }
    else if (g < 1179648)      { cast8(ffw2, W5, g - 655360); }
}

// ---------------------------------------------------------------------------
// bf16 MFMA GEMM (m97 structure): C = A @ B^T. A: MxK, B: NxK, both rowmajor
// bf16. Block = 4 waves, 128 x BN tile, BK=32, global_load_lds width-16.
// EMODE 0: f32 out (+bias). EMODE 1: QKV scatter -> bf16 Qac/Qbd/K/Vt.
// EMODE 2: bf16 R scatter. EMODE 3: bf16 out (+bias, +relu if ACT).
// ---------------------------------------------------------------------------
template<int EMODE, int ACT, int BN>
__global__ __launch_bounds__(256)
void gemm_mfma(const ushort_t* __restrict__ A, const ushort_t* __restrict__ B,
               const float* __restrict__ bias,
               void* __restrict__ O0, void* __restrict__ O1,
               void* __restrict__ O2, void* __restrict__ O3,
               const float* __restrict__ rwb, const float* __restrict__ rrb,
               int M, int N, int K)
{
    constexpr int JT = BN / 32;
    __shared__ ushort_t At[128 * 32];
    __shared__ ushort_t Bt[BN * 32];

    const int tid  = threadIdx.x;
    const int lane = tid & 63;
    const int w    = tid >> 6;
    const int lr   = lane & 15;
    const int quad = lane >> 4;
    const int m0   = blockIdx.x * 128;
    const int n0   = blockIdx.y * BN;
    const int wm0  = (w >> 1) * 64;
    const int wn0  = (w & 1) * (BN / 2);

    f32x4 acc[4][JT];
#pragma unroll
    for (int it = 0; it < 4; ++it)
#pragma unroll
        for (int jt = 0; jt < JT; ++jt) acc[it][jt] = (f32x4){0.f, 0.f, 0.f, 0.f};

    const int srow = lane >> 2;
    const int scol = (lane & 3) << 3;
    const ushort_t* Ag = A + (size_t)(m0 + w * 32 + srow) * K + scol;
    ushort_t* lA0 = At + (w * 32) * 32;
    ushort_t* lA1 = At + (w * 32 + 16) * 32;
    const ushort_t* Bg;
    ushort_t *lB0, *lB1 = nullptr;
    if (BN == 128) {
        Bg  = B + (size_t)(n0 + w * 32 + srow) * K + scol;
        lB0 = Bt + (w * 32) * 32;
        lB1 = Bt + (w * 32 + 16) * 32;
    } else {
        Bg  = B + (size_t)(n0 + w * 16 + srow) * K + scol;
        lB0 = Bt + (w * 16) * 32;
    }

    const ushort_t* Ato = At + (wm0 + lr) * 32 + quad * 8;
    const ushort_t* Bto = Bt + (wn0 + lr) * 32 + quad * 8;

    for (int k0 = 0; k0 < K; k0 += 32) {
        __syncthreads();
        gload_lds16(Ag + k0, lA0);
        gload_lds16(Ag + (size_t)16 * K + k0, lA1);
        gload_lds16(Bg + k0, lB0);
        if (BN == 128) gload_lds16(Bg + (size_t)16 * K + k0, lB1);
        __syncthreads();

        short8 af[4], bf[JT];
#pragma unroll
        for (int it = 0; it < 4; ++it)
            af[it] = *(const short8*)(Ato + it * 16 * 32);
#pragma unroll
        for (int jt = 0; jt < JT; ++jt)
            bf[jt] = *(const short8*)(Bto + jt * 16 * 32);
#pragma unroll
        for (int it = 0; it < 4; ++it)
#pragma unroll
            for (int jt = 0; jt < JT; ++jt)
                acc[it][jt] = __builtin_amdgcn_mfma_f32_16x16x32_bf16(
                    af[it], bf[jt], acc[it][jt], 0, 0, 0);
    }

#pragma unroll
    for (int it = 0; it < 4; ++it)
#pragma unroll
        for (int jt = 0; jt < JT; ++jt)
#pragma unroll
            for (int rg = 0; rg < 4; ++rg) {
                const int m = m0 + wm0 + it * 16 + quad * 4 + rg;
                const int n = n0 + wn0 + jt * 16 + lr;
                float v = acc[it][jt][rg];
                if (EMODE == 0) {
                    if (bias) v += bias[n];
                    ((float*)O0)[(size_t)m * N + n] = v;
                } else if (EMODE == 1) {
                    const int j = m >> 1, b = m & 1;
                    const int part = n >> 10, hh = (n >> 6) & 15, d = n & 63;
                    if (part == 0) {
                        if (j >= MLEN) {
                            const int qi = j - MLEN;
                            const size_t qidx = (((size_t)(b * NH + hh)) * QLEN + qi) * DH + d;
                            ((ushort_t*)O0)[qidx] = f2bf(v + rwb[hh * DH + d]);
                            ((ushort_t*)O1)[qidx] = f2bf(v + rrb[hh * DH + d]);
                        }
                    } else if (part == 1) {
                        ((ushort_t*)O2)[(((size_t)(b * NH + hh)) * KLEN + j) * DH + d] = f2bf(v);
                    } else {
                        ((ushort_t*)O3)[(((size_t)(b * NH + hh)) * DH + d) * KLEN + j] = f2bf(v);
                    }
                } else if (EMODE == 2) {
                    const int hh = n >> 6, d = n & 63;
                    ((ushort_t*)O0)[(((size_t)hh) * KLEN + m) * DH + d] = f2bf(v);
                } else {
                    v += bias[n];
                    if (ACT == 1) v = fmaxf(v, 0.f);
                    ((ushort_t*)O0)[(size_t)m * N + n] = f2bf(v);
                }
            }
}

// ---------------------------------------------------------------------------
// MFMA flash attention with TransformerXL rel-shift.
// Bw is bf16 (LDS 47616 B -> 3 blocks/CU). Q-tiles remapped so blocks p and
// p+256 (same CU) get complementary chunk counts (sum = 49) -> balanced.
// Softmax in exp2 domain.
// ---------------------------------------------------------------------------
__global__ __launch_bounds__(256)
void attn_mfma(const ushort_t* __restrict__ Qac, const ushort_t* __restrict__ Qbd,
               const ushort_t* __restrict__ Kb, const ushort_t* __restrict__ Vt,
               const ushort_t* __restrict__ Rb, ushort_t* __restrict__ AV)
{
    __shared__ ushort_t Kt[64][72];
    __shared__ ushort_t Rt[128][72];
    __shared__ ushort_t Vl[64][72];
    __shared__ ushort_t Bw[4][16][84];   // bf16 scores

    const int tid  = threadIdx.x;
    const int lane = tid & 63;
    const int w    = tid >> 6;
    const int lr   = lane & 15;
    const int quad = lane >> 4;
    const int bh   = blockIdx.y;
    // complementary pairing: blocks p and p+256 share a CU and get qt, 15-qt
    const int qt   = (bh & 16) ? (15 - (int)blockIdx.x) : (int)blockIdx.x;
    const int i0   = qt << 6;
    const int h    = bh & 15;
    const int b    = bh >> 4;

    short8 qaf[2], qbf[2];
    {
        const size_t rowoff = ((size_t)bh * QLEN + i0 + w * 16 + lr) * DH;
#pragma unroll
        for (int kt = 0; kt < 2; ++kt) {
            qaf[kt] = *(const short8*)(Qac + rowoff + kt * 32 + quad * 8);
            qbf[kt] = *(const short8*)(Qbd + rowoff + kt * 32 + quad * 8);
        }
    }

    f32x4 O[4];
#pragma unroll
    for (int nt = 0; nt < 4; ++nt) O[nt] = (f32x4){0.f, 0.f, 0.f, 0.f};
    float m_run = -3.4e38f, l_run = 0.f;

    const int nc  = qt + 17;
    const int stw = 3 - w;
    const float SC = 0.125f * 1.44269504f;   // scale * log2(e), exp2 domain
    const ushort_t* Kh = Kb + (size_t)bh * KLEN * DH;
    const ushort_t* Vh = Vt + (size_t)bh * DH * KLEN;
    const ushort_t* Rh = Rb + (size_t)h * KLEN * DH;

    for (int c = 0; c < nc; ++c) {
        const int j0 = c << 6;
        const int wb = 960 - i0 + j0;
        __syncthreads();
#pragma unroll
        for (int t = 0; t < 2; ++t) {
            int f = tid + (t << 8);
            int row = f >> 3, c8 = (f & 7) << 3;
            *(int4*)&Kt[row][c8] = *(const int4*)(Kh + (size_t)(j0 + row) * DH + c8);
        }
#pragma unroll
        for (int t = 0; t < 2; ++t) {
            int f = tid + (t << 8);
            int d = f >> 3, c8 = (f & 7) << 3;
            *(int4*)&Vl[d][c8] = *(const int4*)(Vh + (size_t)d * KLEN + j0 + c8);
        }
        {
            const int npass = (c == 0) ? 4 : 2;
            const int gb    = (c == 0) ? wb : wb + 64;
            for (int t = 0; t < npass; ++t) {
                int f = tid + (t << 8);
                int rl2 = f >> 3, c8 = (f & 7) << 3;
                int g = gb + rl2;
                int gc = g > (KLEN - 1) ? (KLEN - 1) : g;
                *(int4*)&Rt[g & 127][c8] = *(const int4*)(Rh + (size_t)gc * DH + c8);
            }
        }
        __syncthreads();

        // BD -> Bw (bf16)
#pragma unroll
        for (int ctl = 0; ctl < 5; ++ctl) {
            const int wr = (stw + ctl) * 16 + lr;
            const int ring = (wb + wr) & 127;
            f32x4 z = (f32x4){0.f, 0.f, 0.f, 0.f};
#pragma unroll
            for (int kt = 0; kt < 2; ++kt) {
                short8 rb2 = *(const short8*)&Rt[ring][kt * 32 + quad * 8];
                z = __builtin_amdgcn_mfma_f32_16x16x32_bf16(qbf[kt], rb2, z, 0, 0, 0);
            }
#pragma unroll
            for (int rg = 0; rg < 4; ++rg)
                Bw[w][quad * 4 + rg][ctl * 16 + lr] = f2bf(z[rg]);
        }
        // AC: RMW-add at shifted position (bf16)
#pragma unroll
        for (int ct = 0; ct < 4; ++ct) {
            f32x4 z = (f32x4){0.f, 0.f, 0.f, 0.f};
#pragma unroll
            for (int kt = 0; kt < 2; ++kt) {
                short8 kb2 = *(const short8*)&Kt[ct * 16 + lr][kt * 32 + quad * 8];
                z = __builtin_amdgcn_mfma_f32_16x16x32_bf16(qaf[kt], kb2, z, 0, 0, 0);
            }
#pragma unroll
            for (int rg = 0; rg < 4; ++rg) {
                const int rrow = quad * 4 + rg;
                ushort_t* p = &Bw[w][rrow][ct * 16 + lr + 15 - rrow];
                *p = f2bf(bf2f(*p) + z[rg]);
            }
        }

        const int lim = i0 + w * 16 + lr + 1024 - j0;
        float pv[16];
        float mx = -3.4e38f;
#pragma unroll
        for (int kt = 0; kt < 2; ++kt)
#pragma unroll
            for (int t = 0; t < 8; ++t) {
                const int jj = kt * 32 + quad * 8 + t;
                float s = bf2f(Bw[w][lr][jj + 15 - lr]) * SC;
                s = (jj > lim) ? -3.4e38f : s;
                pv[kt * 8 + t] = s;
                mx = fmaxf(mx, s);
            }
        mx = fmaxf(mx, __shfl_xor(mx, 16, 64));
        mx = fmaxf(mx, __shfl_xor(mx, 32, 64));
        const float m_new = fmaxf(m_run, mx);
        float ps = 0.f;
        short8 pf[2];
#pragma unroll
        for (int kt = 0; kt < 2; ++kt)
#pragma unroll
            for (int t = 0; t < 8; ++t) {
                const float e = exp2f(pv[kt * 8 + t] - m_new);
                ps += e;
                pf[kt][t] = (short)f2bf(e);
            }
        ps += __shfl_xor(ps, 16, 64);
        ps += __shfl_xor(ps, 32, 64);
        const float alpha = exp2f(m_run - m_new);
        m_run = m_new;
        l_run = l_run * alpha + ps;

        float ar[4];
#pragma unroll
        for (int rg = 0; rg < 4; ++rg)
            ar[rg] = __shfl(alpha, quad * 4 + rg, 64);
#pragma unroll
        for (int nt = 0; nt < 4; ++nt) {
            O[nt][0] *= ar[0]; O[nt][1] *= ar[1];
            O[nt][2] *= ar[2]; O[nt][3] *= ar[3];
        }
#pragma unroll
        for (int kt = 0; kt < 2; ++kt)
#pragma unroll
            for (int nt = 0; nt < 4; ++nt) {
                short8 vb = *(const short8*)&Vl[nt * 16 + lr][kt * 32 + quad * 8];
                O[nt] = __builtin_amdgcn_mfma_f32_16x16x32_bf16(pf[kt], vb, O[nt], 0, 0, 0);
            }
    }

    float rlv[4];
#pragma unroll
    for (int rg = 0; rg < 4; ++rg)
        rlv[rg] = 1.f / __shfl(l_run, quad * 4 + rg, 64);
#pragma unroll
    for (int nt = 0; nt < 4; ++nt)
#pragma unroll
        for (int rg = 0; rg < 4; ++rg) {
            const int i = i0 + w * 16 + quad * 4 + rg;
            AV[((size_t)i * BSZc + b) * DM + h * DH + nt * 16 + lr] = f2bf(O[nt][rg] * rlv[rg]);
        }
}

// ---------------------------------------------------------------------------
// out = LayerNorm(X + Y); optional bf16 secondary output
// ---------------------------------------------------------------------------
__global__ __launch_bounds__(256)
void add_ln(const float* __restrict__ X, const float* __restrict__ Y,
            const float* __restrict__ gg, const float* __restrict__ bb,
            float* __restrict__ out, ushort_t* __restrict__ outb)
{
    const int row  = blockIdx.x;
    const int tid  = threadIdx.x;
    const int lane = tid & 63;
    const int w    = tid >> 6;
    __shared__ float ssum[4], ssq[4];

    const float4 xv = ((const float4*)(X + (size_t)row * DM))[tid];
    const float4 yv = ((const float4*)(Y + (size_t)row * DM))[tid];
    const float v0 = xv.x + yv.x, v1 = xv.y + yv.y;
    const float v2 = xv.z + yv.z, v3 = xv.w + yv.w;
    float s = v0 + v1 + v2 + v3;
    float q = v0 * v0 + v1 * v1 + v2 * v2 + v3 * v3;
#pragma unroll
    for (int off = 32; off > 0; off >>= 1) {
        s += __shfl_xor(s, off, 64);
        q += __shfl_xor(q, off, 64);
    }
    if (lane == 0) { ssum[w] = s; ssq[w] = q; }
    __syncthreads();
    s = ssum[0] + ssum[1] + ssum[2] + ssum[3];
    q = ssq[0] + ssq[1] + ssq[2] + ssq[3];
    const float mean = s * (1.f / DM);
    const float var  = q * (1.f / DM) - mean * mean;
    const float rs   = rsqrtf(var + 1e-5f);
    const float4 g4 = ((const float4*)gg)[tid];
    const float4 b4 = ((const float4*)bb)[tid];
    float4 ov;
    ov.x = (v0 - mean) * rs * g4.x + b4.x;
    ov.y = (v1 - mean) * rs * g4.y + b4.y;
    ov.z = (v2 - mean) * rs * g4.z + b4.z;
    ov.w = (v3 - mean) * rs * g4.w + b4.w;
    ((float4*)(out + (size_t)row * DM))[tid] = ov;
    if (outb) {
        ushort_t* p = outb + (size_t)row * DM + tid * 4;
        p[0] = f2bf(ov.x); p[1] = f2bf(ov.y);
        p[2] = f2bf(ov.z); p[3] = f2bf(ov.w);
    }
}

// ---------------------------------------------------------------------------
extern "C" void kernel_launch(void* const* d_in, const int* in_sizes, int n_in,
                              void* d_out, int out_size, void* d_ws, size_t ws_size,
                              hipStream_t stream)
{
    (void)in_sizes; (void)n_in; (void)out_size; (void)ws_size;
    const float* w      = (const float*)d_in[0];
    const float* r      = (const float*)d_in[1];
    const float* mems   = (const float*)d_in[2];
    // d_in[3] attn_mask: deterministic (j > i + MLEN), applied analytically
    const float* qkv_w  = (const float*)d_in[4];
    const float* rnet_w = (const float*)d_in[5];
    const float* o_w    = (const float*)d_in[6];
    const float* r_r_b  = (const float*)d_in[7];
    const float* r_w_b  = (const float*)d_in[8];
    const float* ln1g   = (const float*)d_in[9];
    const float* ln1b   = (const float*)d_in[10];
    const float* ffw1   = (const float*)d_in[11];
    const float* ffb1   = (const float*)d_in[12];
    const float* ffw2   = (const float*)d_in[13];
    const float* ffb2   = (const float*)d_in[14];
    const float* ln2g   = (const float*)d_in[15];
    const float* ln2b   = (const float*)d_in[16];
    float* out = (float*)d_out;

    char* wsb = (char*)d_ws;
    const size_t MB = 1024 * 1024;
    // ---- workspace layout, live ranges verified against launch order ----
    ushort_t* W1    = (ushort_t*)(wsb + 0 * MB);   // qkv_w bf16   0-6   [dead after step 1]
    ushort_t* W2    = (ushort_t*)(wsb + 6 * MB);   // rnet_w bf16  6-8   [dead after step 2]
    ushort_t* Acat  = (ushort_t*)(wsb + 8 * MB);   // cat bf16     8-16  [dead after step 1]
    ushort_t* Rsrc  = (ushort_t*)(wsb + 16 * MB);  // r bf16       16-20 [dead after step 2]
    ushort_t* Qac   = (ushort_t*)(wsb + 20 * MB);  //              20-24 [dead after step 3]
    ushort_t* Qbd   = (ushort_t*)(wsb + 24 * MB);  //              24-28 [dead after step 3]
    ushort_t* Kbf   = (ushort_t*)(wsb + 28 * MB);  //              28-36 [dead after step 3]
    ushort_t* Vt    = (ushort_t*)(wsb + 36 * MB);  //              36-44 [dead after step 3]
    ushort_t* Rh    = (ushort_t*)(wsb + 44 * MB);  //              44-48 [dead after step 3]
    ushort_t* AVec  = (ushort_t*)(wsb + 0 * MB);   // 0-4  (over W1)        live 3->4
    ushort_t* W3    = (ushort_t*)(wsb + 4 * MB);   // 4-6  (over W1)        live cast2->4
    float*    AOut  = (float*)(wsb + 8 * MB);      // 8-16 (over Acat)      live 4->5
    float*    Hbuf  = (float*)(wsb + 16 * MB);     // 16-24 (Rsrc/Qac)      live 5->8
    ushort_t* Hbf   = (ushort_t*)(wsb + 24 * MB);  // 24-28 (Qbd)           live 5->6
    ushort_t* W4    = (ushort_t*)(wsb + 28 * MB);  // 28-36 (Kbf)           live cast2->6
    ushort_t* FFbf  = (ushort_t*)(wsb + 36 * MB);  // 36-52 (Vt/Rh)         live 6->7
    ushort_t* W5    = (ushort_t*)(wsb + 52 * MB);  // 52-60 (virgin)        live cast2->7
    float*    Core  = (float*)(wsb + 0 * MB);      // 0-8  (AVec/W3 dead)   live 7->8
    // peak 60 MB

    dim3 blk(256);

    // casts for phase 1 (one launch)
    cast_phase1<<<dim3(5120), blk, 0, stream>>>(qkv_w, rnet_w, mems, w, r,
                                                W1, W2, Acat, Rsrc);

    // 1. QKV projection -> Qac/Qbd (bias added), K, V^T
    gemm_mfma<1, 0, 128><<<dim3(32, 24), blk, 0, stream>>>(
        Acat, W1, nullptr, Qac, Qbd, Kbf, Vt, r_w_b, r_r_b, 4096, 3072, 1024);

    // 2. r_head_k -> R[h][klen][dh]
    gemm_mfma<2, 0, 64><<<dim3(16, 16), blk, 0, stream>>>(
        Rsrc, W2, nullptr, Rh, nullptr, nullptr, nullptr, nullptr, nullptr,
        2048, 1024, 1024);

    // 3. MFMA flash attention -> bf16 attn_vec
    attn_mfma<<<dim3(QLEN / 64, BSZc * NH), blk, 0, stream>>>(
        Qac, Qbd, Kbf, Vt, Rh, AVec);

    // casts for phase 2 (after attn: W4 overlays Kbf, W3 overlays dead W1)
    cast_phase2<<<dim3(4608), blk, 0, stream>>>(o_w, ffw1, ffw2, W3, W4, W5);

    // 4. output projection (f32 out)
    gemm_mfma<0, 0, 64><<<dim3(16, 16), blk, 0, stream>>>(
        AVec, W3, nullptr, AOut, nullptr, nullptr, nullptr, nullptr, nullptr,
        2048, 1024, 1024);

    // 5. h = LN(w + attn_out)  (f32 + bf16 copies)
    add_ln<<<dim3(2 * QLEN), blk, 0, stream>>>(w, AOut, ln1g, ln1b, Hbuf, Hbf);

    // 6. FF1: relu(h @ ff_w1^T + b1) -> bf16
    gemm_mfma<3, 1, 128><<<dim3(16, 32), blk, 0, stream>>>(
        Hbf, W4, ffb1, FFbf, nullptr, nullptr, nullptr, nullptr, nullptr,
        2048, 4096, 1024);

    // 7. FF2 -> f32 Core
    gemm_mfma<0, 0, 64><<<dim3(16, 16), blk, 0, stream>>>(
        FFbf, W5, ffb2, Core, nullptr, nullptr, nullptr, nullptr, nullptr,
        2048, 1024, 4096);

    // 8. out = LN(h + core)
    add_ln<<<dim3(2 * QLEN), blk, 0, stream>>>(Hbuf, Core, ln2g, ln2b, out, nullptr);
}

// Round 6
// 440.628 us; speedup vs baseline: 4.9756x; 1.0440x over previous
//
#include <hip/hip_runtime.h>
#include <math.h>

#define QLEN 1024
#define MLEN 1024
#define KLEN 2048
#define BSZc 2
#define NH 16
#define DH 64
#define DM 1024
#define DI 4096

typedef unsigned short ushort_t;
typedef __attribute__((ext_vector_type(8))) short short8;
typedef __attribute__((ext_vector_type(4))) float f32x4;

__device__ __forceinline__ ushort_t f2bf(float x) {
    unsigned int u = __float_as_uint(x);
    unsigned int r = (u + 0x7FFFu + ((u >> 16) & 1u)) >> 16;
    return (ushort_t)r;
}

__device__ __forceinline__ void gload_lds16(const ushort_t* g, ushort_t* l) {
    __builtin_amdgcn_global_load_lds(
        (const __attribute__((address_space(1))) unsigned int*)g,
        (__attribute__((address_space(3))) unsigned int*)l,
        16, 0, 0);
}

// ---------------------------------------------------------------------------
// segmented f32 -> bf16 casts (one launch per phase)
// ---------------------------------------------------------------------------
__device__ __forceinline__ void cast8(const float* s, ushort_t* d, int g) {
    const float4 a = *(const float4*)(s + g * 8);
    const float4 b = *(const float4*)(s + g * 8 + 4);
    short8 o;
    o[0] = (short)f2bf(a.x); o[1] = (short)f2bf(a.y);
    o[2] = (short)f2bf(a.z); o[3] = (short)f2bf(a.w);
    o[4] = (short)f2bf(b.x); o[5] = (short)f2bf(b.y);
    o[6] = (short)f2bf(b.z); o[7] = (short)f2bf(b.w);
    *(short8*)(d + g * 8) = o;
}

__global__ __launch_bounds__(256)
void cast_phase1(const float* __restrict__ qkv_w, const float* __restrict__ rnet_w,
                 const float* __restrict__ mems, const float* __restrict__ w,
                 const float* __restrict__ r,
                 ushort_t* __restrict__ W1, ushort_t* __restrict__ W2,
                 ushort_t* __restrict__ Acat, ushort_t* __restrict__ Rsrc)
{
    int g = blockIdx.x * 256 + threadIdx.x;
    if (g < 393216)            { cast8(qkv_w,  W1,              g); }
    else if (g < 524288)       { cast8(rnet_w, W2,              g - 393216); }
    else if (g < 786432)       { cast8(mems,   Acat,            g - 524288); }
    else if (g < 1048576)      { cast8(w,      Acat + 2097152,  g - 786432); }
    else if (g < 1310720)      { cast8(r,      Rsrc,            g - 1048576); }
}

__global__ __launch_bounds__(256)
void cast_phase2(const float* __restrict__ o_w, const float* __restrict__ ffw1,
                 const float* __restrict__ ffw2,
                 ushort_t* __restrict__ W3, ushort_t* __restrict__ W4,
                 ushort_t* __restrict__ W5)
{
    int g = blockIdx.x * 256 + threadIdx.x;
    if (g < 131072)            { cast8(o_w,  W3, g); }
    else if (g < 655360)       { cast8(ffw1, W4, g - 131072); }
    else if (g < 1179648)      { cast8(ffw2, W5, g - 655360); }
}

// ---------------------------------------------------------------------------
// bf16 MFMA GEMM (m97 structure): C = A @ B^T. 128 x BN tile, BK=32.
// EMODE 0: f32 out (+bias). EMODE 3: bf16 out (+bias, +relu if ACT).
// ---------------------------------------------------------------------------
template<int EMODE, int ACT, int BN>
__global__ __launch_bounds__(256)
void gemm_mfma(const ushort_t* __restrict__ A, const ushort_t* __restrict__ B,
               const float* __restrict__ bias,
               void* __restrict__ O0, int M, int N, int K)
{
    constexpr int JT = BN / 32;
    __shared__ ushort_t At[128 * 32];
    __shared__ ushort_t Bt[BN * 32];

    const int tid  = threadIdx.x;
    const int lane = tid & 63;
    const int w    = tid >> 6;
    const int lr   = lane & 15;
    const int quad = lane >> 4;
    const int m0   = blockIdx.x * 128;
    const int n0   = blockIdx.y * BN;
    const int wm0  = (w >> 1) * 64;
    const int wn0  = (w & 1) * (BN / 2);

    f32x4 acc[4][JT];
#pragma unroll
    for (int it = 0; it < 4; ++it)
#pragma unroll
        for (int jt = 0; jt < JT; ++jt) acc[it][jt] = (f32x4){0.f, 0.f, 0.f, 0.f};

    const int srow = lane >> 2;
    const int scol = (lane & 3) << 3;
    const ushort_t* Ag = A + (size_t)(m0 + w * 32 + srow) * K + scol;
    ushort_t* lA0 = At + (w * 32) * 32;
    ushort_t* lA1 = At + (w * 32 + 16) * 32;
    const ushort_t* Bg;
    ushort_t *lB0, *lB1 = nullptr;
    if (BN == 128) {
        Bg  = B + (size_t)(n0 + w * 32 + srow) * K + scol;
        lB0 = Bt + (w * 32) * 32;
        lB1 = Bt + (w * 32 + 16) * 32;
    } else {
        Bg  = B + (size_t)(n0 + w * 16 + srow) * K + scol;
        lB0 = Bt + (w * 16) * 32;
    }

    const ushort_t* Ato = At + (wm0 + lr) * 32 + quad * 8;
    const ushort_t* Bto = Bt + (wn0 + lr) * 32 + quad * 8;

    for (int k0 = 0; k0 < K; k0 += 32) {
        __syncthreads();
        gload_lds16(Ag + k0, lA0);
        gload_lds16(Ag + (size_t)16 * K + k0, lA1);
        gload_lds16(Bg + k0, lB0);
        if (BN == 128) gload_lds16(Bg + (size_t)16 * K + k0, lB1);
        __syncthreads();

        short8 af[4], bf[JT];
#pragma unroll
        for (int it = 0; it < 4; ++it)
            af[it] = *(const short8*)(Ato + it * 16 * 32);
#pragma unroll
        for (int jt = 0; jt < JT; ++jt)
            bf[jt] = *(const short8*)(Bto + jt * 16 * 32);
#pragma unroll
        for (int it = 0; it < 4; ++it)
#pragma unroll
            for (int jt = 0; jt < JT; ++jt)
                acc[it][jt] = __builtin_amdgcn_mfma_f32_16x16x32_bf16(
                    af[it], bf[jt], acc[it][jt], 0, 0, 0);
    }

#pragma unroll
    for (int it = 0; it < 4; ++it)
#pragma unroll
        for (int jt = 0; jt < JT; ++jt)
#pragma unroll
            for (int rg = 0; rg < 4; ++rg) {
                const int m = m0 + wm0 + it * 16 + quad * 4 + rg;
                const int n = n0 + wn0 + jt * 16 + lr;
                float v = acc[it][jt][rg];
                if (EMODE == 0) {
                    if (bias) v += bias[n];
                    ((float*)O0)[(size_t)m * N + n] = v;
                } else {
                    v += bias[n];
                    if (ACT == 1) v = fmaxf(v, 0.f);
                    ((ushort_t*)O0)[(size_t)m * N + n] = f2bf(v);
                }
            }
}

// ---------------------------------------------------------------------------
// Fused QKV + r_net GEMM. Flat grid: bid<768 -> QKV (M=4096,N=3072),
// else r_net (M=2048,N=1024). Both K=1024, 128x128 tiles.
// QKV epilogue scatters -> bf16 Qac/Qbd (biases), K, V^T; rnet -> R[h][j][d].
// ---------------------------------------------------------------------------
__global__ __launch_bounds__(256)
void gemm_qkvr(const ushort_t* __restrict__ Acat, const ushort_t* __restrict__ W1,
               const ushort_t* __restrict__ Rsrc, const ushort_t* __restrict__ W2,
               ushort_t* __restrict__ Qac, ushort_t* __restrict__ Qbd,
               ushort_t* __restrict__ Kbf, ushort_t* __restrict__ Vtb,
               ushort_t* __restrict__ Rh,
               const float* __restrict__ rwb, const float* __restrict__ rrb)
{
    __shared__ ushort_t At[128 * 32];
    __shared__ ushort_t Bt[128 * 32];

    const int bid  = blockIdx.x;
    const bool isr = bid >= 768;
    const ushort_t* A; const ushort_t* B; int m0, n0;
    if (!isr) { A = Acat; B = W1; m0 = (bid & 31) * 128; n0 = (bid >> 5) * 128; }
    else { int t = bid - 768; A = Rsrc; B = W2; m0 = (t & 15) * 128; n0 = (t >> 4) * 128; }
    const int K = 1024;

    const int tid  = threadIdx.x;
    const int lane = tid & 63;
    const int w    = tid >> 6;
    const int lr   = lane & 15;
    const int quad = lane >> 4;
    const int wm0  = (w >> 1) * 64;
    const int wn0  = (w & 1) * 64;

    f32x4 acc[4][4];
#pragma unroll
    for (int it = 0; it < 4; ++it)
#pragma unroll
        for (int jt = 0; jt < 4; ++jt) acc[it][jt] = (f32x4){0.f, 0.f, 0.f, 0.f};

    const int srow = lane >> 2;
    const int scol = (lane & 3) << 3;
    const ushort_t* Ag = A + (size_t)(m0 + w * 32 + srow) * K + scol;
    const ushort_t* Bg = B + (size_t)(n0 + w * 32 + srow) * K + scol;
    ushort_t* lA0 = At + (w * 32) * 32;
    ushort_t* lA1 = At + (w * 32 + 16) * 32;
    ushort_t* lB0 = Bt + (w * 32) * 32;
    ushort_t* lB1 = Bt + (w * 32 + 16) * 32;

    const ushort_t* Ato = At + (wm0 + lr) * 32 + quad * 8;
    const ushort_t* Bto = Bt + (wn0 + lr) * 32 + quad * 8;

    for (int k0 = 0; k0 < K; k0 += 32) {
        __syncthreads();
        gload_lds16(Ag + k0, lA0);
        gload_lds16(Ag + (size_t)16 * K + k0, lA1);
        gload_lds16(Bg + k0, lB0);
        gload_lds16(Bg + (size_t)16 * K + k0, lB1);
        __syncthreads();

        short8 af[4], bf[4];
#pragma unroll
        for (int it = 0; it < 4; ++it)
            af[it] = *(const short8*)(Ato + it * 16 * 32);
#pragma unroll
        for (int jt = 0; jt < 4; ++jt)
            bf[jt] = *(const short8*)(Bto + jt * 16 * 32);
#pragma unroll
        for (int it = 0; it < 4; ++it)
#pragma unroll
            for (int jt = 0; jt < 4; ++jt)
                acc[it][jt] = __builtin_amdgcn_mfma_f32_16x16x32_bf16(
                    af[it], bf[jt], acc[it][jt], 0, 0, 0);
    }

#pragma unroll
    for (int it = 0; it < 4; ++it)
#pragma unroll
        for (int jt = 0; jt < 4; ++jt)
#pragma unroll
            for (int rg = 0; rg < 4; ++rg) {
                const int m = m0 + wm0 + it * 16 + quad * 4 + rg;
                const int n = n0 + wn0 + jt * 16 + lr;
                const float v = acc[it][jt][rg];
                if (!isr) {
                    const int j = m >> 1, b = m & 1;
                    const int part = n >> 10, hh = (n >> 6) & 15, d = n & 63;
                    if (part == 0) {
                        if (j >= MLEN) {
                            const int qi = j - MLEN;
                            const size_t qidx = (((size_t)(b * NH + hh)) * QLEN + qi) * DH + d;
                            Qac[qidx] = f2bf(v + rwb[hh * DH + d]);
                            Qbd[qidx] = f2bf(v + rrb[hh * DH + d]);
                        }
                    } else if (part == 1) {
                        Kbf[(((size_t)(b * NH + hh)) * KLEN + j) * DH + d] = f2bf(v);
                    } else {
                        Vtb[(((size_t)(b * NH + hh)) * DH + d) * KLEN + j] = f2bf(v);
                    }
                } else {
                    const int hh = n >> 6, d = n & 63;
                    Rh[(((size_t)hh) * KLEN + m) * DH + d] = f2bf(v);
                }
            }
}

// ---------------------------------------------------------------------------
// MFMA flash attention with TransformerXL rel-shift, split-K x2.
// Grid (16 qt, 2 s, 32 bh). Block (qt,s,bh) handles chunks c≡s (mod 2) of
// nc = qt+17 (online softmax is order-agnostic). Partial unnormalized O and
// per-row (m,l) written to f32 workspace; attn_merge combines.
// Bw in f32 (bf16 Bw measured slower: VALU converts on DS-bound path).
// ---------------------------------------------------------------------------
__global__ __launch_bounds__(256)
void attn_mfma(const ushort_t* __restrict__ Qac, const ushort_t* __restrict__ Qbd,
               const ushort_t* __restrict__ Kb, const ushort_t* __restrict__ Vt,
               const ushort_t* __restrict__ Rb,
               float* __restrict__ Op0, float* __restrict__ Op1,
               float* __restrict__ Mp, float* __restrict__ Lp)
{
    __shared__ ushort_t Kt[64][72];
    __shared__ ushort_t Rt[128][72];
    __shared__ ushort_t Vl[64][72];
    __shared__ float    Bw[4][16][84];

    const int tid  = threadIdx.x;
    const int lane = tid & 63;
    const int w    = tid >> 6;
    const int lr   = lane & 15;
    const int quad = lane >> 4;
    const int qt   = blockIdx.x;
    const int s    = blockIdx.y;
    const int bh   = blockIdx.z;
    const int i0   = qt << 6;
    const int h    = bh & 15;
    const int b    = bh >> 4;

    short8 qaf[2], qbf[2];
    {
        const size_t rowoff = ((size_t)bh * QLEN + i0 + w * 16 + lr) * DH;
#pragma unroll
        for (int kt = 0; kt < 2; ++kt) {
            qaf[kt] = *(const short8*)(Qac + rowoff + kt * 32 + quad * 8);
            qbf[kt] = *(const short8*)(Qbd + rowoff + kt * 32 + quad * 8);
        }
    }

    f32x4 O[4];
#pragma unroll
    for (int nt = 0; nt < 4; ++nt) O[nt] = (f32x4){0.f, 0.f, 0.f, 0.f};
    float m_run = -3.4e38f, l_run = 0.f;

    const int nc  = qt + 17;
    const int stw = 3 - w;
    const float SC = 0.125f * 1.44269504f;   // scale * log2(e)
    const ushort_t* Kh = Kb + (size_t)bh * KLEN * DH;
    const ushort_t* Vh = Vt + (size_t)bh * DH * KLEN;
    const ushort_t* Rhp = Rb + (size_t)h * KLEN * DH;

    for (int c = s; c < nc; c += 2) {
        const int j0 = c << 6;
        const int wb = 960 - i0 + j0;      // window base (global R row of wr=0)
        __syncthreads();
#pragma unroll
        for (int t = 0; t < 2; ++t) {
            int f = tid + (t << 8);
            int row = f >> 3, c8 = (f & 7) << 3;
            *(int4*)&Kt[row][c8] = *(const int4*)(Kh + (size_t)(j0 + row) * DH + c8);
        }
#pragma unroll
        for (int t = 0; t < 2; ++t) {
            int f = tid + (t << 8);
            int d = f >> 3, c8 = (f & 7) << 3;
            *(int4*)&Vl[d][c8] = *(const int4*)(Vh + (size_t)d * KLEN + j0 + c8);
        }
#pragma unroll
        for (int t = 0; t < 4; ++t) {      // full 128-row R window
            int f = tid + (t << 8);
            int rl2 = f >> 3, c8 = (f & 7) << 3;
            int g = wb + rl2;
            int gc = g > (KLEN - 1) ? (KLEN - 1) : g;  // clamped rows only feed masked cells
            *(int4*)&Rt[rl2][c8] = *(const int4*)(Rhp + (size_t)gc * DH + c8);
        }
        __syncthreads();

        // BD: 5 window col-tiles -> Bw (f32)
#pragma unroll
        for (int ctl = 0; ctl < 5; ++ctl) {
            const int wr = (stw + ctl) * 16 + lr;
            f32x4 z = (f32x4){0.f, 0.f, 0.f, 0.f};
#pragma unroll
            for (int kt = 0; kt < 2; ++kt) {
                short8 rb2 = *(const short8*)&Rt[wr][kt * 32 + quad * 8];
                z = __builtin_amdgcn_mfma_f32_16x16x32_bf16(qbf[kt], rb2, z, 0, 0, 0);
            }
#pragma unroll
            for (int rg = 0; rg < 4; ++rg)
                Bw[w][quad * 4 + rg][ctl * 16 + lr] = z[rg];
        }
        // AC: add at shifted position cb = jj + 15 - row
#pragma unroll
        for (int ct = 0; ct < 4; ++ct) {
            f32x4 z = (f32x4){0.f, 0.f, 0.f, 0.f};
#pragma unroll
            for (int kt = 0; kt < 2; ++kt) {
                short8 kb2 = *(const short8*)&Kt[ct * 16 + lr][kt * 32 + quad * 8];
                z = __builtin_amdgcn_mfma_f32_16x16x32_bf16(qaf[kt], kb2, z, 0, 0, 0);
            }
#pragma unroll
            for (int rg = 0; rg < 4; ++rg) {
                const int rrow = quad * 4 + rg;
                Bw[w][rrow][ct * 16 + lr + 15 - rrow] += z[rg];
            }
        }

        const int lim = i0 + w * 16 + lr + 1024 - j0;
        float pv[16];
        float mx = -3.4e38f;
#pragma unroll
        for (int kt = 0; kt < 2; ++kt)
#pragma unroll
            for (int t = 0; t < 8; ++t) {
                const int jj = kt * 32 + quad * 8 + t;
                float sv = Bw[w][lr][jj + 15 - lr] * SC;
                sv = (jj > lim) ? -3.4e38f : sv;
                pv[kt * 8 + t] = sv;
                mx = fmaxf(mx, sv);
            }
        mx = fmaxf(mx, __shfl_xor(mx, 16, 64));
        mx = fmaxf(mx, __shfl_xor(mx, 32, 64));
        const float m_new = fmaxf(m_run, mx);
        float ps = 0.f;
        short8 pf[2];
#pragma unroll
        for (int kt = 0; kt < 2; ++kt)
#pragma unroll
            for (int t = 0; t < 8; ++t) {
                const float e = exp2f(pv[kt * 8 + t] - m_new);
                ps += e;
                pf[kt][t] = (short)f2bf(e);
            }
        ps += __shfl_xor(ps, 16, 64);
        ps += __shfl_xor(ps, 32, 64);
        const float alpha = exp2f(m_run - m_new);
        m_run = m_new;
        l_run = l_run * alpha + ps;

        float ar[4];
#pragma unroll
        for (int rg = 0; rg < 4; ++rg)
            ar[rg] = __shfl(alpha, quad * 4 + rg, 64);
#pragma unroll
        for (int nt = 0; nt < 4; ++nt) {
            O[nt][0] *= ar[0]; O[nt][1] *= ar[1];
            O[nt][2] *= ar[2]; O[nt][3] *= ar[3];
        }
#pragma unroll
        for (int kt = 0; kt < 2; ++kt)
#pragma unroll
            for (int nt = 0; nt < 4; ++nt) {
                short8 vb = *(const short8*)&Vl[nt * 16 + lr][kt * 32 + quad * 8];
                O[nt] = __builtin_amdgcn_mfma_f32_16x16x32_bf16(pf[kt], vb, O[nt], 0, 0, 0);
            }
    }

    // write partials (unnormalized O + per-row m,l)
    if (quad == 0) {
        const size_t mi = ((size_t)s * 32 + bh) * QLEN + i0 + w * 16 + lr;
        Mp[mi] = m_run;
        Lp[mi] = l_run;
    }
    float* Op = s ? Op1 : Op0;
#pragma unroll
    for (int nt = 0; nt < 4; ++nt)
#pragma unroll
        for (int rg = 0; rg < 4; ++rg) {
            const int i = i0 + w * 16 + quad * 4 + rg;
            Op[((size_t)i * BSZc + b) * DM + h * DH + nt * 16 + lr] = O[nt][rg];
        }
}

// ---------------------------------------------------------------------------
// merge split-K partials -> bf16 attn_vec
// ---------------------------------------------------------------------------
__global__ __launch_bounds__(256)
void attn_merge(const float* __restrict__ O0, const float* __restrict__ O1,
                const float* __restrict__ Mp, const float* __restrict__ Lp,
                ushort_t* __restrict__ AV)
{
    const int row = blockIdx.x;           // i*BSZ + b
    const int tid = threadIdx.x;
    const int i = row >> 1, b = row & 1;
    const int h = tid >> 4;
    const int bh = b * NH + h;
    const size_t mi = (size_t)bh * QLEN + i;
    const float m1 = Mp[mi],            l1 = Lp[mi];
    const float m2 = Mp[32 * QLEN + mi], l2 = Lp[32 * QLEN + mi];
    const float M = fmaxf(m1, m2);
    const float a1 = exp2f(m1 - M), a2 = exp2f(m2 - M);
    const float rl = 1.f / (l1 * a1 + l2 * a2);
    const float f1 = a1 * rl, f2 = a2 * rl;
    const float4 o1 = ((const float4*)(O0 + (size_t)row * DM))[tid];
    const float4 o2 = ((const float4*)(O1 + (size_t)row * DM))[tid];
    ushort_t* p = AV + (size_t)row * DM + tid * 4;
    p[0] = f2bf(o1.x * f1 + o2.x * f2);
    p[1] = f2bf(o1.y * f1 + o2.y * f2);
    p[2] = f2bf(o1.z * f1 + o2.z * f2);
    p[3] = f2bf(o1.w * f1 + o2.w * f2);
}

// ---------------------------------------------------------------------------
// out = LayerNorm(X + Y); optional bf16 secondary output
// ---------------------------------------------------------------------------
__global__ __launch_bounds__(256)
void add_ln(const float* __restrict__ X, const float* __restrict__ Y,
            const float* __restrict__ gg, const float* __restrict__ bb,
            float* __restrict__ out, ushort_t* __restrict__ outb)
{
    const int row  = blockIdx.x;
    const int tid  = threadIdx.x;
    const int lane = tid & 63;
    const int w    = tid >> 6;
    __shared__ float ssum[4], ssq[4];

    const float4 xv = ((const float4*)(X + (size_t)row * DM))[tid];
    const float4 yv = ((const float4*)(Y + (size_t)row * DM))[tid];
    const float v0 = xv.x + yv.x, v1 = xv.y + yv.y;
    const float v2 = xv.z + yv.z, v3 = xv.w + yv.w;
    float s = v0 + v1 + v2 + v3;
    float q = v0 * v0 + v1 * v1 + v2 * v2 + v3 * v3;
#pragma unroll
    for (int off = 32; off > 0; off >>= 1) {
        s += __shfl_xor(s, off, 64);
        q += __shfl_xor(q, off, 64);
    }
    if (lane == 0) { ssum[w] = s; ssq[w] = q; }
    __syncthreads();
    s = ssum[0] + ssum[1] + ssum[2] + ssum[3];
    q = ssq[0] + ssq[1] + ssq[2] + ssq[3];
    const float mean = s * (1.f / DM);
    const float var  = q * (1.f / DM) - mean * mean;
    const float rs   = rsqrtf(var + 1e-5f);
    const float4 g4 = ((const float4*)gg)[tid];
    const float4 b4 = ((const float4*)bb)[tid];
    float4 ov;
    ov.x = (v0 - mean) * rs * g4.x + b4.x;
    ov.y = (v1 - mean) * rs * g4.y + b4.y;
    ov.z = (v2 - mean) * rs * g4.z + b4.z;
    ov.w = (v3 - mean) * rs * g4.w + b4.w;
    ((float4*)(out + (size_t)row * DM))[tid] = ov;
    if (outb) {
        ushort_t* p = outb + (size_t)row * DM + tid * 4;
        p[0] = f2bf(ov.x); p[1] = f2bf(ov.y);
        p[2] = f2bf(ov.z); p[3] = f2bf(ov.w);
    }
}

// ---------------------------------------------------------------------------
extern "C" void kernel_launch(void* const* d_in, const int* in_sizes, int n_in,
                              void* d_out, int out_size, void* d_ws, size_t ws_size,
                              hipStream_t stream)
{
    (void)in_sizes; (void)n_in; (void)out_size; (void)ws_size;
    const float* w      = (const float*)d_in[0];
    const float* r      = (const float*)d_in[1];
    const float* mems   = (const float*)d_in[2];
    // d_in[3] attn_mask: deterministic (j > i + MLEN), applied analytically
    const float* qkv_w  = (const float*)d_in[4];
    const float* rnet_w = (const float*)d_in[5];
    const float* o_w    = (const float*)d_in[6];
    const float* r_r_b  = (const float*)d_in[7];
    const float* r_w_b  = (const float*)d_in[8];
    const float* ln1g   = (const float*)d_in[9];
    const float* ln1b   = (const float*)d_in[10];
    const float* ffw1   = (const float*)d_in[11];
    const float* ffb1   = (const float*)d_in[12];
    const float* ffw2   = (const float*)d_in[13];
    const float* ffb2   = (const float*)d_in[14];
    const float* ln2g   = (const float*)d_in[15];
    const float* ln2b   = (const float*)d_in[16];
    float* out = (float*)d_out;

    char* wsb = (char*)d_ws;
    const size_t MB = 1024 * 1024;
    // ---- workspace layout, live ranges verified against launch order ----
    ushort_t* W1    = (ushort_t*)(wsb + 0 * MB);   // 0-6    dead after qkvr
    ushort_t* W2    = (ushort_t*)(wsb + 6 * MB);   // 6-8    dead after qkvr
    ushort_t* Acat  = (ushort_t*)(wsb + 8 * MB);   // 8-16   dead after qkvr
    ushort_t* Rsrc  = (ushort_t*)(wsb + 16 * MB);  // 16-20  dead after qkvr
    ushort_t* Qac   = (ushort_t*)(wsb + 20 * MB);  // 20-24  dead after attn
    ushort_t* Qbd   = (ushort_t*)(wsb + 24 * MB);  // 24-28  dead after attn
    ushort_t* Kbf   = (ushort_t*)(wsb + 28 * MB);  // 28-36  dead after attn
    ushort_t* Vt    = (ushort_t*)(wsb + 36 * MB);  // 36-44  dead after attn
    ushort_t* Rh    = (ushort_t*)(wsb + 44 * MB);  // 44-48  dead after attn
    float*    Op0   = (float*)(wsb + 48 * MB);     // 48-56  attn -> merge
    float*    Op1   = (float*)(wsb + 56 * MB);     // 56-64  attn -> merge
    float*    Mp    = (float*)(wsb + 4 * MB);      // 4-4.25 (over dead W1) attn -> merge
    float*    Lp    = (float*)(wsb + 4 * MB + 512 * 1024); // 4.5-4.75
    ushort_t* AVec  = (ushort_t*)(wsb + 0 * MB);   // 0-4   merge -> o-proj
    ushort_t* W3    = (ushort_t*)(wsb + 4 * MB);   // 4-6   cast2 -> o-proj (over Mp/Lp, dead)
    float*    AOut  = (float*)(wsb + 8 * MB);      // 8-16  o-proj -> ln1
    float*    Hbuf  = (float*)(wsb + 16 * MB);     // 16-24 ln1 -> ln2
    ushort_t* Hbf   = (ushort_t*)(wsb + 24 * MB);  // 24-28 ln1 -> ff1
    ushort_t* W4    = (ushort_t*)(wsb + 28 * MB);  // 28-36 cast2 -> ff1
    ushort_t* FFbf  = (ushort_t*)(wsb + 36 * MB);  // 36-52 ff1 -> ff2 (over Vt/Rh/Op0 head)
    ushort_t* W5    = (ushort_t*)(wsb + 52 * MB);  // 52-60 cast2 -> ff2 (over Op0 tail/Op1 head, dead)
    float*    Core  = (float*)(wsb + 0 * MB);      // 0-8   ff2 -> ln2 (AVec/W3 dead)
    // peak 64 MB

    dim3 blk(256);

    // casts for phase 1
    cast_phase1<<<dim3(5120), blk, 0, stream>>>(qkv_w, rnet_w, mems, w, r,
                                                W1, W2, Acat, Rsrc);

    // 1+2. fused QKV + r_net projections
    gemm_qkvr<<<dim3(896), blk, 0, stream>>>(
        Acat, W1, Rsrc, W2, Qac, Qbd, Kbf, Vt, Rh, r_w_b, r_r_b);

    // 3. MFMA flash attention, split-K x2 -> partials
    attn_mfma<<<dim3(16, 2, 32), blk, 0, stream>>>(
        Qac, Qbd, Kbf, Vt, Rh, Op0, Op1, Mp, Lp);

    // 3b. merge partials -> bf16 attn_vec
    attn_merge<<<dim3(2048), blk, 0, stream>>>(Op0, Op1, Mp, Lp, AVec);

    // casts for phase 2
    cast_phase2<<<dim3(4608), blk, 0, stream>>>(o_w, ffw1, ffw2, W3, W4, W5);

    // 4. output projection (f32 out)
    gemm_mfma<0, 0, 64><<<dim3(16, 16), blk, 0, stream>>>(
        AVec, W3, nullptr, AOut, 2048, 1024, 1024);

    // 5. h = LN(w + attn_out)  (f32 + bf16 copies)
    add_ln<<<dim3(2 * QLEN), blk, 0, stream>>>(w, AOut, ln1g, ln1b, Hbuf, Hbf);

    // 6. FF1: relu(h @ ff_w1^T + b1) -> bf16
    gemm_mfma<3, 1, 128><<<dim3(16, 32), blk, 0, stream>>>(
        Hbf, W4, ffb1, FFbf, 2048, 4096, 1024);

    // 7. FF2 -> f32 Core
    gemm_mfma<0, 0, 64><<<dim3(16, 16), blk, 0, stream>>>(
        FFbf, W5, ffb2, Core, 2048, 1024, 4096);

    // 8. out = LN(h + core)
    add_ln<<<dim3(2 * QLEN), blk, 0, stream>>>(Hbuf, Core, ln2g, ln2b, out, nullptr);
}

// Round 7
// 437.168 us; speedup vs baseline: 5.0150x; 1.0079x over previous
//
#include <hip/hip_runtime.h>
#include <math.h>

#define QLEN 1024
#define MLEN 1024
#define KLEN 2048
#define BSZc 2
#define NH 16
#define DH 64
#define DM 1024
#define DI 4096

typedef unsigned short ushort_t;
typedef __attribute__((ext_vector_type(8))) short short8;
typedef __attribute__((ext_vector_type(4))) float f32x4;

__device__ __forceinline__ ushort_t f2bf(float x) {
    unsigned int u = __float_as_uint(x);
    unsigned int r = (u + 0x7FFFu + ((u >> 16) & 1u)) >> 16;
    return (ushort_t)r;
}

__device__ __forceinline__ void gload_lds16(const ushort_t* g, ushort_t* l) {
    __builtin_amdgcn_global_load_lds(
        (const __attribute__((address_space(1))) unsigned int*)g,
        (__attribute__((address_space(3))) unsigned int*)l,
        16, 0, 0);
}

// ---------------------------------------------------------------------------
// segmented f32 -> bf16 casts (one launch per phase)
// ---------------------------------------------------------------------------
__device__ __forceinline__ void cast8(const float* s, ushort_t* d, int g) {
    const float4 a = *(const float4*)(s + g * 8);
    const float4 b = *(const float4*)(s + g * 8 + 4);
    short8 o;
    o[0] = (short)f2bf(a.x); o[1] = (short)f2bf(a.y);
    o[2] = (short)f2bf(a.z); o[3] = (short)f2bf(a.w);
    o[4] = (short)f2bf(b.x); o[5] = (short)f2bf(b.y);
    o[6] = (short)f2bf(b.z); o[7] = (short)f2bf(b.w);
    *(short8*)(d + g * 8) = o;
}

__global__ __launch_bounds__(256)
void cast_phase1(const float* __restrict__ qkv_w, const float* __restrict__ rnet_w,
                 const float* __restrict__ mems, const float* __restrict__ w,
                 const float* __restrict__ r,
                 ushort_t* __restrict__ W1, ushort_t* __restrict__ W2,
                 ushort_t* __restrict__ Acat, ushort_t* __restrict__ Rsrc)
{
    int g = blockIdx.x * 256 + threadIdx.x;
    if (g < 393216)            { cast8(qkv_w,  W1,              g); }
    else if (g < 524288)       { cast8(rnet_w, W2,              g - 393216); }
    else if (g < 786432)       { cast8(mems,   Acat,            g - 524288); }
    else if (g < 1048576)      { cast8(w,      Acat + 2097152,  g - 786432); }
    else if (g < 1310720)      { cast8(r,      Rsrc,            g - 1048576); }
}

__global__ __launch_bounds__(256)
void cast_phase2(const float* __restrict__ o_w, const float* __restrict__ ffw1,
                 const float* __restrict__ ffw2,
                 ushort_t* __restrict__ W3, ushort_t* __restrict__ W4,
                 ushort_t* __restrict__ W5)
{
    int g = blockIdx.x * 256 + threadIdx.x;
    if (g < 131072)            { cast8(o_w,  W3, g); }
    else if (g < 655360)       { cast8(ffw1, W4, g - 131072); }
    else if (g < 1179648)      { cast8(ffw2, W5, g - 655360); }
}

// ---------------------------------------------------------------------------
// bf16 MFMA GEMM: C = A @ B^T. 128 x BN tile, BK=64 (two BK=32 buffer pairs,
// one barrier pair per 64-K: halves barrier-drain stalls vs round 6).
// SPLIT>1: blockIdx.z selects K-slice [z*Ks, (z+1)*Ks); partial f32 out to
// O0v (z=0) / O1v (z=1); bias added only on z==0.
// EMODE 0: f32 out (+bias). EMODE 3: bf16 out (+bias, +relu if ACT).
// ---------------------------------------------------------------------------
template<int EMODE, int ACT, int BN, int SPLIT>
__global__ __launch_bounds__(256)
void gemm_mfma(const ushort_t* __restrict__ A, const ushort_t* __restrict__ B,
               const float* __restrict__ bias,
               void* __restrict__ O0v, void* __restrict__ O1v,
               int M, int N, int Ks, int lda, int ldb)
{
    constexpr int JT = BN / 32;
    __shared__ ushort_t At0[128 * 32];
    __shared__ ushort_t At1[128 * 32];
    __shared__ ushort_t Bt0[BN * 32];
    __shared__ ushort_t Bt1[BN * 32];

    const int tid  = threadIdx.x;
    const int lane = tid & 63;
    const int w    = tid >> 6;
    const int lr   = lane & 15;
    const int quad = lane >> 4;
    const int m0   = blockIdx.x * 128;
    const int n0   = blockIdx.y * BN;
    const int z    = (SPLIT > 1) ? (int)blockIdx.z : 0;
    const int kbase = z * Ks;
    const int wm0  = (w >> 1) * 64;
    const int wn0  = (w & 1) * (BN / 2);

    f32x4 acc[4][JT];
#pragma unroll
    for (int it = 0; it < 4; ++it)
#pragma unroll
        for (int jt = 0; jt < JT; ++jt) acc[it][jt] = (f32x4){0.f, 0.f, 0.f, 0.f};

    const int srow = lane >> 2;
    const int scol = (lane & 3) << 3;
    const ushort_t* Ag = A + (size_t)(m0 + w * 32 + srow) * lda + kbase + scol;
    ushort_t* a00 = At0 + (w * 32) * 32;
    ushort_t* a01 = At0 + (w * 32 + 16) * 32;
    ushort_t* a10 = At1 + (w * 32) * 32;
    ushort_t* a11 = At1 + (w * 32 + 16) * 32;
    const ushort_t* Bg;
    ushort_t *b00, *b01 = nullptr, *b10, *b11 = nullptr;
    if (BN == 128) {
        Bg  = B + (size_t)(n0 + w * 32 + srow) * ldb + kbase + scol;
        b00 = Bt0 + (w * 32) * 32;
        b01 = Bt0 + (w * 32 + 16) * 32;
        b10 = Bt1 + (w * 32) * 32;
        b11 = Bt1 + (w * 32 + 16) * 32;
    } else {
        Bg  = B + (size_t)(n0 + w * 16 + srow) * ldb + kbase + scol;
        b00 = Bt0 + (w * 16) * 32;
        b10 = Bt1 + (w * 16) * 32;
    }

    const ushort_t* Ato0 = At0 + (wm0 + lr) * 32 + quad * 8;
    const ushort_t* Ato1 = At1 + (wm0 + lr) * 32 + quad * 8;
    const ushort_t* Bto0 = Bt0 + (wn0 + lr) * 32 + quad * 8;
    const ushort_t* Bto1 = Bt1 + (wn0 + lr) * 32 + quad * 8;

    for (int k0 = 0; k0 < Ks; k0 += 64) {
        __syncthreads();
        gload_lds16(Ag + k0, a00);
        gload_lds16(Ag + (size_t)16 * lda + k0, a01);
        gload_lds16(Ag + k0 + 32, a10);
        gload_lds16(Ag + (size_t)16 * lda + k0 + 32, a11);
        if (BN == 128) {
            gload_lds16(Bg + k0, b00);
            gload_lds16(Bg + (size_t)16 * ldb + k0, b01);
            gload_lds16(Bg + k0 + 32, b10);
            gload_lds16(Bg + (size_t)16 * ldb + k0 + 32, b11);
        } else {
            gload_lds16(Bg + k0, b00);
            gload_lds16(Bg + k0 + 32, b10);
        }
        __syncthreads();

        short8 af[4], bf[JT];
#pragma unroll
        for (int it = 0; it < 4; ++it)
            af[it] = *(const short8*)(Ato0 + it * 16 * 32);
#pragma unroll
        for (int jt = 0; jt < JT; ++jt)
            bf[jt] = *(const short8*)(Bto0 + jt * 16 * 32);
#pragma unroll
        for (int it = 0; it < 4; ++it)
#pragma unroll
            for (int jt = 0; jt < JT; ++jt)
                acc[it][jt] = __builtin_amdgcn_mfma_f32_16x16x32_bf16(
                    af[it], bf[jt], acc[it][jt], 0, 0, 0);
#pragma unroll
        for (int it = 0; it < 4; ++it)
            af[it] = *(const short8*)(Ato1 + it * 16 * 32);
#pragma unroll
        for (int jt = 0; jt < JT; ++jt)
            bf[jt] = *(const short8*)(Bto1 + jt * 16 * 32);
#pragma unroll
        for (int it = 0; it < 4; ++it)
#pragma unroll
            for (int jt = 0; jt < JT; ++jt)
                acc[it][jt] = __builtin_amdgcn_mfma_f32_16x16x32_bf16(
                    af[it], bf[jt], acc[it][jt], 0, 0, 0);
    }

#pragma unroll
    for (int it = 0; it < 4; ++it)
#pragma unroll
        for (int jt = 0; jt < JT; ++jt)
#pragma unroll
            for (int rg = 0; rg < 4; ++rg) {
                const int m = m0 + wm0 + it * 16 + quad * 4 + rg;
                const int n = n0 + wn0 + jt * 16 + lr;
                float v = acc[it][jt][rg];
                if (EMODE == 0) {
                    float* dst = (float*)(z ? O1v : O0v);
                    if (bias && z == 0) v += bias[n];
                    dst[(size_t)m * N + n] = v;
                } else {
                    v += bias[n];
                    if (ACT == 1) v = fmaxf(v, 0.f);
                    ((ushort_t*)O0v)[(size_t)m * N + n] = f2bf(v);
                }
            }
}

// ---------------------------------------------------------------------------
// Fused QKV + r_net GEMM (BK=32, unchanged from round 6 — known good).
// ---------------------------------------------------------------------------
__global__ __launch_bounds__(256)
void gemm_qkvr(const ushort_t* __restrict__ Acat, const ushort_t* __restrict__ W1,
               const ushort_t* __restrict__ Rsrc, const ushort_t* __restrict__ W2,
               ushort_t* __restrict__ Qac, ushort_t* __restrict__ Qbd,
               ushort_t* __restrict__ Kbf, ushort_t* __restrict__ Vtb,
               ushort_t* __restrict__ Rh,
               const float* __restrict__ rwb, const float* __restrict__ rrb)
{
    __shared__ ushort_t At[128 * 32];
    __shared__ ushort_t Bt[128 * 32];

    const int bid  = blockIdx.x;
    const bool isr = bid >= 768;
    const ushort_t* A; const ushort_t* B; int m0, n0;
    if (!isr) { A = Acat; B = W1; m0 = (bid & 31) * 128; n0 = (bid >> 5) * 128; }
    else { int t = bid - 768; A = Rsrc; B = W2; m0 = (t & 15) * 128; n0 = (t >> 4) * 128; }
    const int K = 1024;

    const int tid  = threadIdx.x;
    const int lane = tid & 63;
    const int w    = tid >> 6;
    const int lr   = lane & 15;
    const int quad = lane >> 4;
    const int wm0  = (w >> 1) * 64;
    const int wn0  = (w & 1) * 64;

    f32x4 acc[4][4];
#pragma unroll
    for (int it = 0; it < 4; ++it)
#pragma unroll
        for (int jt = 0; jt < 4; ++jt) acc[it][jt] = (f32x4){0.f, 0.f, 0.f, 0.f};

    const int srow = lane >> 2;
    const int scol = (lane & 3) << 3;
    const ushort_t* Ag = A + (size_t)(m0 + w * 32 + srow) * K + scol;
    const ushort_t* Bg = B + (size_t)(n0 + w * 32 + srow) * K + scol;
    ushort_t* lA0 = At + (w * 32) * 32;
    ushort_t* lA1 = At + (w * 32 + 16) * 32;
    ushort_t* lB0 = Bt + (w * 32) * 32;
    ushort_t* lB1 = Bt + (w * 32 + 16) * 32;

    const ushort_t* Ato = At + (wm0 + lr) * 32 + quad * 8;
    const ushort_t* Bto = Bt + (wn0 + lr) * 32 + quad * 8;

    for (int k0 = 0; k0 < K; k0 += 32) {
        __syncthreads();
        gload_lds16(Ag + k0, lA0);
        gload_lds16(Ag + (size_t)16 * K + k0, lA1);
        gload_lds16(Bg + k0, lB0);
        gload_lds16(Bg + (size_t)16 * K + k0, lB1);
        __syncthreads();

        short8 af[4], bf[4];
#pragma unroll
        for (int it = 0; it < 4; ++it)
            af[it] = *(const short8*)(Ato + it * 16 * 32);
#pragma unroll
        for (int jt = 0; jt < 4; ++jt)
            bf[jt] = *(const short8*)(Bto + jt * 16 * 32);
#pragma unroll
        for (int it = 0; it < 4; ++it)
#pragma unroll
            for (int jt = 0; jt < 4; ++jt)
                acc[it][jt] = __builtin_amdgcn_mfma_f32_16x16x32_bf16(
                    af[it], bf[jt], acc[it][jt], 0, 0, 0);
    }

#pragma unroll
    for (int it = 0; it < 4; ++it)
#pragma unroll
        for (int jt = 0; jt < 4; ++jt)
#pragma unroll
            for (int rg = 0; rg < 4; ++rg) {
                const int m = m0 + wm0 + it * 16 + quad * 4 + rg;
                const int n = n0 + wn0 + jt * 16 + lr;
                const float v = acc[it][jt][rg];
                if (!isr) {
                    const int j = m >> 1, b = m & 1;
                    const int part = n >> 10, hh = (n >> 6) & 15, d = n & 63;
                    if (part == 0) {
                        if (j >= MLEN) {
                            const int qi = j - MLEN;
                            const size_t qidx = (((size_t)(b * NH + hh)) * QLEN + qi) * DH + d;
                            Qac[qidx] = f2bf(v + rwb[hh * DH + d]);
                            Qbd[qidx] = f2bf(v + rrb[hh * DH + d]);
                        }
                    } else if (part == 1) {
                        Kbf[(((size_t)(b * NH + hh)) * KLEN + j) * DH + d] = f2bf(v);
                    } else {
                        Vtb[(((size_t)(b * NH + hh)) * DH + d) * KLEN + j] = f2bf(v);
                    }
                } else {
                    const int hh = n >> 6, d = n & 63;
                    Rh[(((size_t)hh) * KLEN + m) * DH + d] = f2bf(v);
                }
            }
}

// ---------------------------------------------------------------------------
// MFMA flash attention with TransformerXL rel-shift, split-K x2.
// K and V B-fragments loaded DIRECTLY from global (16 rows x 16B/lane; the
// tiles are L2-resident) -> LDS = Rt + Bw = 39936 B -> 4 blocks/CU, and
// __launch_bounds__(256,4) caps VGPR at 128 so 16 waves/CU are reachable.
// Grid 1024 blocks == full single-round residency at 4 blocks/CU.
// ---------------------------------------------------------------------------
__global__ __launch_bounds__(256, 4)
void attn_mfma(const ushort_t* __restrict__ Qac, const ushort_t* __restrict__ Qbd,
               const ushort_t* __restrict__ Kb, const ushort_t* __restrict__ Vt,
               const ushort_t* __restrict__ Rb,
               float* __restrict__ Op0, float* __restrict__ Op1,
               float* __restrict__ Mp, float* __restrict__ Lp)
{
    __shared__ ushort_t Rt[128][72];   // R window, padded: conflict-free b128
    __shared__ float    Bw[4][16][84]; // per-wave shifted score strip

    const int tid  = threadIdx.x;
    const int lane = tid & 63;
    const int w    = tid >> 6;
    const int lr   = lane & 15;
    const int quad = lane >> 4;
    const int qt   = blockIdx.x;
    const int s    = blockIdx.y;
    const int bh   = blockIdx.z;
    const int i0   = qt << 6;
    const int h    = bh & 15;
    const int b    = bh >> 4;

    short8 qaf[2], qbf[2];
    {
        const size_t rowoff = ((size_t)bh * QLEN + i0 + w * 16 + lr) * DH;
#pragma unroll
        for (int kt = 0; kt < 2; ++kt) {
            qaf[kt] = *(const short8*)(Qac + rowoff + kt * 32 + quad * 8);
            qbf[kt] = *(const short8*)(Qbd + rowoff + kt * 32 + quad * 8);
        }
    }

    f32x4 O[4];
#pragma unroll
    for (int nt = 0; nt < 4; ++nt) O[nt] = (f32x4){0.f, 0.f, 0.f, 0.f};
    float m_run = -3.4e38f, l_run = 0.f;

    const int nc  = qt + 17;
    const int stw = 3 - w;
    const float SC = 0.125f * 1.44269504f;   // scale * log2(e)
    const ushort_t* Kh = Kb + (size_t)bh * KLEN * DH;
    const ushort_t* Vh = Vt + (size_t)bh * DH * KLEN;
    const ushort_t* Rhp = Rb + (size_t)h * KLEN * DH;

    for (int c = s; c < nc; c += 2) {
        const int j0 = c << 6;
        const int wb = 960 - i0 + j0;      // window base (global R row of wr=0)
        __syncthreads();
#pragma unroll
        for (int t = 0; t < 4; ++t) {      // stage 128-row R window
            int f = tid + (t << 8);
            int rl2 = f >> 3, c8 = (f & 7) << 3;
            int g = wb + rl2;
            int gc = g > (KLEN - 1) ? (KLEN - 1) : g;  // clamped rows feed only masked cells
            *(int4*)&Rt[rl2][c8] = *(const int4*)(Rhp + (size_t)gc * DH + c8);
        }
        __syncthreads();

        // BD: 5 window col-tiles -> Bw (f32)
#pragma unroll
        for (int ctl = 0; ctl < 5; ++ctl) {
            const int wr = (stw + ctl) * 16 + lr;
            f32x4 z = (f32x4){0.f, 0.f, 0.f, 0.f};
#pragma unroll
            for (int kt = 0; kt < 2; ++kt) {
                short8 rb2 = *(const short8*)&Rt[wr][kt * 32 + quad * 8];
                z = __builtin_amdgcn_mfma_f32_16x16x32_bf16(qbf[kt], rb2, z, 0, 0, 0);
            }
#pragma unroll
            for (int rg = 0; rg < 4; ++rg)
                Bw[w][quad * 4 + rg][ctl * 16 + lr] = z[rg];
        }
        // AC: B-frag straight from global K; add at shifted col jj + 15 - row
#pragma unroll
        for (int ct = 0; ct < 4; ++ct) {
            f32x4 z = (f32x4){0.f, 0.f, 0.f, 0.f};
#pragma unroll
            for (int kt = 0; kt < 2; ++kt) {
                short8 kb2 = *(const short8*)(Kh + (size_t)(j0 + ct * 16 + lr) * DH + kt * 32 + quad * 8);
                z = __builtin_amdgcn_mfma_f32_16x16x32_bf16(qaf[kt], kb2, z, 0, 0, 0);
            }
#pragma unroll
            for (int rg = 0; rg < 4; ++rg) {
                const int rrow = quad * 4 + rg;
                Bw[w][rrow][ct * 16 + lr + 15 - rrow] += z[rg];
            }
        }

        const int lim = i0 + w * 16 + lr + 1024 - j0;
        float pv[16];
        float mx = -3.4e38f;
#pragma unroll
        for (int kt = 0; kt < 2; ++kt)
#pragma unroll
            for (int t = 0; t < 8; ++t) {
                const int jj = kt * 32 + quad * 8 + t;
                float sv = Bw[w][lr][jj + 15 - lr] * SC;
                sv = (jj > lim) ? -3.4e38f : sv;
                pv[kt * 8 + t] = sv;
                mx = fmaxf(mx, sv);
            }
        mx = fmaxf(mx, __shfl_xor(mx, 16, 64));
        mx = fmaxf(mx, __shfl_xor(mx, 32, 64));
        const float m_new = fmaxf(m_run, mx);
        float ps = 0.f;
        short8 pf[2];
#pragma unroll
        for (int kt = 0; kt < 2; ++kt)
#pragma unroll
            for (int t = 0; t < 8; ++t) {
                const float e = exp2f(pv[kt * 8 + t] - m_new);
                ps += e;
                pf[kt][t] = (short)f2bf(e);
            }
        ps += __shfl_xor(ps, 16, 64);
        ps += __shfl_xor(ps, 32, 64);
        const float alpha = exp2f(m_run - m_new);
        m_run = m_new;
        l_run = l_run * alpha + ps;

        float ar[4];
#pragma unroll
        for (int rg = 0; rg < 4; ++rg)
            ar[rg] = __shfl(alpha, quad * 4 + rg, 64);
#pragma unroll
        for (int nt = 0; nt < 4; ++nt) {
            O[nt][0] *= ar[0]; O[nt][1] *= ar[1];
            O[nt][2] *= ar[2]; O[nt][3] *= ar[3];
        }
        // PV: B-frag straight from global V^T
#pragma unroll
        for (int kt = 0; kt < 2; ++kt)
#pragma unroll
            for (int nt = 0; nt < 4; ++nt) {
                short8 vb = *(const short8*)(Vh + (size_t)(nt * 16 + lr) * KLEN + j0 + kt * 32 + quad * 8);
                O[nt] = __builtin_amdgcn_mfma_f32_16x16x32_bf16(pf[kt], vb, O[nt], 0, 0, 0);
            }
    }

    if (quad == 0) {
        const size_t mi = ((size_t)s * 32 + bh) * QLEN + i0 + w * 16 + lr;
        Mp[mi] = m_run;
        Lp[mi] = l_run;
    }
    float* Op = s ? Op1 : Op0;
#pragma unroll
    for (int nt = 0; nt < 4; ++nt)
#pragma unroll
        for (int rg = 0; rg < 4; ++rg) {
            const int i = i0 + w * 16 + quad * 4 + rg;
            Op[((size_t)i * BSZc + b) * DM + h * DH + nt * 16 + lr] = O[nt][rg];
        }
}

// ---------------------------------------------------------------------------
// merge split-K partials -> bf16 attn_vec
// ---------------------------------------------------------------------------
__global__ __launch_bounds__(256)
void attn_merge(const float* __restrict__ O0, const float* __restrict__ O1,
                const float* __restrict__ Mp, const float* __restrict__ Lp,
                ushort_t* __restrict__ AV)
{
    const int row = blockIdx.x;           // i*BSZ + b
    const int tid = threadIdx.x;
    const int i = row >> 1, b = row & 1;
    const int h = tid >> 4;
    const int bh = b * NH + h;
    const size_t mi = (size_t)bh * QLEN + i;
    const float m1 = Mp[mi],             l1 = Lp[mi];
    const float m2 = Mp[32 * QLEN + mi], l2 = Lp[32 * QLEN + mi];
    const float M = fmaxf(m1, m2);
    const float a1 = exp2f(m1 - M), a2 = exp2f(m2 - M);
    const float rl = 1.f / (l1 * a1 + l2 * a2);
    const float f1 = a1 * rl, f2 = a2 * rl;
    const float4 o1 = ((const float4*)(O0 + (size_t)row * DM))[tid];
    const float4 o2 = ((const float4*)(O1 + (size_t)row * DM))[tid];
    ushort_t* p = AV + (size_t)row * DM + tid * 4;
    p[0] = f2bf(o1.x * f1 + o2.x * f2);
    p[1] = f2bf(o1.y * f1 + o2.y * f2);
    p[2] = f2bf(o1.z * f1 + o2.z * f2);
    p[3] = f2bf(o1.w * f1 + o2.w * f2);
}

// ---------------------------------------------------------------------------
// out = LayerNorm(X + Y0 [+ Y1]); optional bf16 secondary output
// ---------------------------------------------------------------------------
__global__ __launch_bounds__(256)
void add_ln(const float* __restrict__ X, const float* __restrict__ Y0,
            const float* __restrict__ Y1,
            const float* __restrict__ gg, const float* __restrict__ bb,
            float* __restrict__ out, ushort_t* __restrict__ outb)
{
    const int row  = blockIdx.x;
    const int tid  = threadIdx.x;
    const int lane = tid & 63;
    const int w    = tid >> 6;
    __shared__ float ssum[4], ssq[4];

    const float4 xv = ((const float4*)(X + (size_t)row * DM))[tid];
    const float4 yv = ((const float4*)(Y0 + (size_t)row * DM))[tid];
    float v0 = xv.x + yv.x, v1 = xv.y + yv.y;
    float v2 = xv.z + yv.z, v3 = xv.w + yv.w;
    if (Y1) {
        const float4 zv = ((const float4*)(Y1 + (size_t)row * DM))[tid];
        v0 += zv.x; v1 += zv.y; v2 += zv.z; v3 += zv.w;
    }
    float s = v0 + v1 + v2 + v3;
    float q = v0 * v0 + v1 * v1 + v2 * v2 + v3 * v3;
#pragma unroll
    for (int off = 32; off > 0; off >>= 1) {
        s += __shfl_xor(s, off, 64);
        q += __shfl_xor(q, off, 64);
    }
    if (lane == 0) { ssum[w] = s; ssq[w] = q; }
    __syncthreads();
    s = ssum[0] + ssum[1] + ssum[2] + ssum[3];
    q = ssq[0] + ssq[1] + ssq[2] + ssq[3];
    const float mean = s * (1.f / DM);
    const float var  = q * (1.f / DM) - mean * mean;
    const float rs   = rsqrtf(var + 1e-5f);
    const float4 g4 = ((const float4*)gg)[tid];
    const float4 b4 = ((const float4*)bb)[tid];
    float4 ov;
    ov.x = (v0 - mean) * rs * g4.x + b4.x;
    ov.y = (v1 - mean) * rs * g4.y + b4.y;
    ov.z = (v2 - mean) * rs * g4.z + b4.z;
    ov.w = (v3 - mean) * rs * g4.w + b4.w;
    ((float4*)(out + (size_t)row * DM))[tid] = ov;
    if (outb) {
        ushort_t* p = outb + (size_t)row * DM + tid * 4;
        p[0] = f2bf(ov.x); p[1] = f2bf(ov.y);
        p[2] = f2bf(ov.z); p[3] = f2bf(ov.w);
    }
}

// ---------------------------------------------------------------------------
extern "C" void kernel_launch(void* const* d_in, const int* in_sizes, int n_in,
                              void* d_out, int out_size, void* d_ws, size_t ws_size,
                              hipStream_t stream)
{
    (void)in_sizes; (void)n_in; (void)out_size; (void)ws_size;
    const float* w      = (const float*)d_in[0];
    const float* r      = (const float*)d_in[1];
    const float* mems   = (const float*)d_in[2];
    // d_in[3] attn_mask: deterministic (j > i + MLEN), applied analytically
    const float* qkv_w  = (const float*)d_in[4];
    const float* rnet_w = (const float*)d_in[5];
    const float* o_w    = (const float*)d_in[6];
    const float* r_r_b  = (const float*)d_in[7];
    const float* r_w_b  = (const float*)d_in[8];
    const float* ln1g   = (const float*)d_in[9];
    const float* ln1b   = (const float*)d_in[10];
    const float* ffw1   = (const float*)d_in[11];
    const float* ffb1   = (const float*)d_in[12];
    const float* ffw2   = (const float*)d_in[13];
    const float* ffb2   = (const float*)d_in[14];
    const float* ln2g   = (const float*)d_in[15];
    const float* ln2b   = (const float*)d_in[16];
    float* out = (float*)d_out;

    char* wsb = (char*)d_ws;
    const size_t MB = 1024 * 1024;
    // ---- workspace layout, live ranges verified against launch order ----
    ushort_t* W1    = (ushort_t*)(wsb + 0 * MB);   // 0-6    dead after qkvr
    ushort_t* W2    = (ushort_t*)(wsb + 6 * MB);   // 6-8    dead after qkvr
    ushort_t* Acat  = (ushort_t*)(wsb + 8 * MB);   // 8-16   dead after qkvr
    ushort_t* Rsrc  = (ushort_t*)(wsb + 16 * MB);  // 16-20  dead after qkvr
    ushort_t* Qac   = (ushort_t*)(wsb + 20 * MB);  // 20-24  dead after attn
    ushort_t* Qbd   = (ushort_t*)(wsb + 24 * MB);  // 24-28  dead after attn
    ushort_t* Kbf   = (ushort_t*)(wsb + 28 * MB);  // 28-36  dead after attn
    ushort_t* Vt    = (ushort_t*)(wsb + 36 * MB);  // 36-44  dead after attn
    ushort_t* Rh    = (ushort_t*)(wsb + 44 * MB);  // 44-48  dead after attn
    float*    Op0   = (float*)(wsb + 48 * MB);     // 48-56  attn -> merge
    float*    Op1   = (float*)(wsb + 56 * MB);     // 56-64  attn -> merge
    float*    Mp    = (float*)(wsb + 4 * MB);      // 4-4.25 (over dead W1)
    float*    Lp    = (float*)(wsb + 4 * MB + 512 * 1024); // 4.5-4.75
    ushort_t* AVec  = (ushort_t*)(wsb + 0 * MB);   // 0-4   merge -> o-proj
    ushort_t* W3    = (ushort_t*)(wsb + 4 * MB);   // 4-6   cast2 -> o-proj (over Mp/Lp dead)
    float*    AOut0 = (float*)(wsb + 8 * MB);      // 8-16  o-proj -> ln1 (over Acat dead)
    float*    AOut1 = (float*)(wsb + 44 * MB);     // 44-52 o-proj -> ln1 (over Rh/Op0-head dead)
    float*    Hbuf  = (float*)(wsb + 16 * MB);     // 16-24 ln1 -> ln2 (over Rsrc/Qac dead)
    ushort_t* Hbf   = (ushort_t*)(wsb + 24 * MB);  // 24-28 ln1 -> ff1 (over Qbd dead)
    ushort_t* W4    = (ushort_t*)(wsb + 28 * MB);  // 28-36 cast2 -> ff1 (over Kbf dead)
    ushort_t* FFbf  = (ushort_t*)(wsb + 36 * MB);  // 36-52 ff1 -> ff2 (over Vt/AOut1 dead)
    ushort_t* W5    = (ushort_t*)(wsb + 52 * MB);  // 52-60 cast2 -> ff2 (over Op0-tail/Op1-head dead)
    float*    Core0 = (float*)(wsb + 0 * MB);      // 0-8   ff2 -> ln2 (AVec/W3 dead)
    float*    Core1 = (float*)(wsb + 8 * MB);      // 8-16  ff2 -> ln2 (AOut0 dead)
    // peak 64 MB

    dim3 blk(256);

    // casts for phase 1
    cast_phase1<<<dim3(5120), blk, 0, stream>>>(qkv_w, rnet_w, mems, w, r,
                                                W1, W2, Acat, Rsrc);

    // 1+2. fused QKV + r_net projections
    gemm_qkvr<<<dim3(896), blk, 0, stream>>>(
        Acat, W1, Rsrc, W2, Qac, Qbd, Kbf, Vt, Rh, r_w_b, r_r_b);

    // 3. MFMA flash attention, split-K x2 -> partials
    attn_mfma<<<dim3(16, 2, 32), blk, 0, stream>>>(
        Qac, Qbd, Kbf, Vt, Rh, Op0, Op1, Mp, Lp);

    // 3b. merge partials -> bf16 attn_vec
    attn_merge<<<dim3(2048), blk, 0, stream>>>(Op0, Op1, Mp, Lp, AVec);

    // casts for phase 2
    cast_phase2<<<dim3(4608), blk, 0, stream>>>(o_w, ffw1, ffw2, W3, W4, W5);

    // 4. output projection, split-K x2 (f32 partials)
    gemm_mfma<0, 0, 64, 2><<<dim3(16, 16, 2), blk, 0, stream>>>(
        AVec, W3, nullptr, AOut0, AOut1, 2048, 1024, 512, 1024, 1024);

    // 5. h = LN(w + AOut0 + AOut1)  (f32 + bf16 copies)
    add_ln<<<dim3(2 * QLEN), blk, 0, stream>>>(w, AOut0, AOut1, ln1g, ln1b, Hbuf, Hbf);

    // 6. FF1: relu(h @ ff_w1^T + b1) -> bf16
    gemm_mfma<3, 1, 128, 1><<<dim3(16, 32), blk, 0, stream>>>(
        Hbf, W4, ffb1, FFbf, nullptr, 2048, 4096, 1024, 1024, 1024);

    // 7. FF2, split-K x2 -> f32 partials
    gemm_mfma<0, 0, 64, 2><<<dim3(16, 16, 2), blk, 0, stream>>>(
        FFbf, W5, ffb2, Core0, Core1, 2048, 1024, 2048, 4096, 4096);

    // 8. out = LN(h + Core0 + Core1)
    add_ln<<<dim3(2 * QLEN), blk, 0, stream>>>(Hbuf, Core0, Core1, ln2g, ln2b, out, nullptr);
}

// Round 8
// 397.169 us; speedup vs baseline: 5.5201x; 1.1007x over previous
//
#include <hip/hip_runtime.h>
#include <math.h>

#define QLEN 1024
#define MLEN 1024
#define KLEN 2048
#define BSZc 2
#define NH 16
#define DH 64
#define DM 1024
#define DI 4096

typedef unsigned short ushort_t;
typedef __attribute__((ext_vector_type(8))) short short8;
typedef __attribute__((ext_vector_type(4))) float f32x4;

__device__ __forceinline__ ushort_t f2bf(float x) {
    unsigned int u = __float_as_uint(x);
    unsigned int r = (u + 0x7FFFu + ((u >> 16) & 1u)) >> 16;
    return (ushort_t)r;
}

__device__ __forceinline__ void gload_lds16(const ushort_t* g, ushort_t* l) {
    __builtin_amdgcn_global_load_lds(
        (const __attribute__((address_space(1))) unsigned int*)g,
        (__attribute__((address_space(3))) unsigned int*)l,
        16, 0, 0);
}

// ---------------------------------------------------------------------------
// segmented f32 -> bf16 casts (one launch per phase)
// ---------------------------------------------------------------------------
__device__ __forceinline__ void cast8(const float* s, ushort_t* d, int g) {
    const float4 a = *(const float4*)(s + g * 8);
    const float4 b = *(const float4*)(s + g * 8 + 4);
    short8 o;
    o[0] = (short)f2bf(a.x); o[1] = (short)f2bf(a.y);
    o[2] = (short)f2bf(a.z); o[3] = (short)f2bf(a.w);
    o[4] = (short)f2bf(b.x); o[5] = (short)f2bf(b.y);
    o[6] = (short)f2bf(b.z); o[7] = (short)f2bf(b.w);
    *(short8*)(d + g * 8) = o;
}

__global__ __launch_bounds__(256)
void cast_phase1(const float* __restrict__ qkv_w, const float* __restrict__ rnet_w,
                 const float* __restrict__ mems, const float* __restrict__ w,
                 const float* __restrict__ r,
                 ushort_t* __restrict__ W1, ushort_t* __restrict__ W2,
                 ushort_t* __restrict__ Acat, ushort_t* __restrict__ Rsrc)
{
    int g = blockIdx.x * 256 + threadIdx.x;
    if (g < 393216)            { cast8(qkv_w,  W1,              g); }
    else if (g < 524288)       { cast8(rnet_w, W2,              g - 393216); }
    else if (g < 786432)       { cast8(mems,   Acat,            g - 524288); }
    else if (g < 1048576)      { cast8(w,      Acat + 2097152,  g - 786432); }
    else if (g < 1310720)      { cast8(r,      Rsrc,            g - 1048576); }
}

__global__ __launch_bounds__(256)
void cast_phase2(const float* __restrict__ o_w, const float* __restrict__ ffw1,
                 const float* __restrict__ ffw2,
                 ushort_t* __restrict__ W3, ushort_t* __restrict__ W4,
                 ushort_t* __restrict__ W5)
{
    int g = blockIdx.x * 256 + threadIdx.x;
    if (g < 131072)            { cast8(o_w,  W3, g); }
    else if (g < 655360)       { cast8(ffw1, W4, g - 131072); }
    else if (g < 1179648)      { cast8(ffw2, W5, g - 655360); }
}

// ---------------------------------------------------------------------------
// bf16 MFMA GEMM: C = A @ B^T. 128 x BN tile, BK=64 (two BK=32 buffer pairs).
// SPLIT>1: blockIdx.z selects K-slice; partial f32 out; bias only on z==0.
// EMODE 0: f32 out (+bias). EMODE 3: bf16 out (+bias, +relu if ACT).
// ---------------------------------------------------------------------------
template<int EMODE, int ACT, int BN, int SPLIT>
__global__ __launch_bounds__(256)
void gemm_mfma(const ushort_t* __restrict__ A, const ushort_t* __restrict__ B,
               const float* __restrict__ bias,
               void* __restrict__ O0v, void* __restrict__ O1v,
               int M, int N, int Ks, int lda, int ldb)
{
    constexpr int JT = BN / 32;
    __shared__ ushort_t At0[128 * 32];
    __shared__ ushort_t At1[128 * 32];
    __shared__ ushort_t Bt0[BN * 32];
    __shared__ ushort_t Bt1[BN * 32];

    const int tid  = threadIdx.x;
    const int lane = tid & 63;
    const int w    = tid >> 6;
    const int lr   = lane & 15;
    const int quad = lane >> 4;
    const int m0   = blockIdx.x * 128;
    const int n0   = blockIdx.y * BN;
    const int z    = (SPLIT > 1) ? (int)blockIdx.z : 0;
    const int kbase = z * Ks;
    const int wm0  = (w >> 1) * 64;
    const int wn0  = (w & 1) * (BN / 2);

    f32x4 acc[4][JT];
#pragma unroll
    for (int it = 0; it < 4; ++it)
#pragma unroll
        for (int jt = 0; jt < JT; ++jt) acc[it][jt] = (f32x4){0.f, 0.f, 0.f, 0.f};

    const int srow = lane >> 2;
    const int scol = (lane & 3) << 3;
    const ushort_t* Ag = A + (size_t)(m0 + w * 32 + srow) * lda + kbase + scol;
    ushort_t* a00 = At0 + (w * 32) * 32;
    ushort_t* a01 = At0 + (w * 32 + 16) * 32;
    ushort_t* a10 = At1 + (w * 32) * 32;
    ushort_t* a11 = At1 + (w * 32 + 16) * 32;
    const ushort_t* Bg;
    ushort_t *b00, *b01 = nullptr, *b10, *b11 = nullptr;
    if (BN == 128) {
        Bg  = B + (size_t)(n0 + w * 32 + srow) * ldb + kbase + scol;
        b00 = Bt0 + (w * 32) * 32;
        b01 = Bt0 + (w * 32 + 16) * 32;
        b10 = Bt1 + (w * 32) * 32;
        b11 = Bt1 + (w * 32 + 16) * 32;
    } else {
        Bg  = B + (size_t)(n0 + w * 16 + srow) * ldb + kbase + scol;
        b00 = Bt0 + (w * 16) * 32;
        b10 = Bt1 + (w * 16) * 32;
    }

    const ushort_t* Ato0 = At0 + (wm0 + lr) * 32 + quad * 8;
    const ushort_t* Ato1 = At1 + (wm0 + lr) * 32 + quad * 8;
    const ushort_t* Bto0 = Bt0 + (wn0 + lr) * 32 + quad * 8;
    const ushort_t* Bto1 = Bt1 + (wn0 + lr) * 32 + quad * 8;

    for (int k0 = 0; k0 < Ks; k0 += 64) {
        __syncthreads();
        gload_lds16(Ag + k0, a00);
        gload_lds16(Ag + (size_t)16 * lda + k0, a01);
        gload_lds16(Ag + k0 + 32, a10);
        gload_lds16(Ag + (size_t)16 * lda + k0 + 32, a11);
        if (BN == 128) {
            gload_lds16(Bg + k0, b00);
            gload_lds16(Bg + (size_t)16 * ldb + k0, b01);
            gload_lds16(Bg + k0 + 32, b10);
            gload_lds16(Bg + (size_t)16 * ldb + k0 + 32, b11);
        } else {
            gload_lds16(Bg + k0, b00);
            gload_lds16(Bg + k0 + 32, b10);
        }
        __syncthreads();

        short8 af[4], bf[JT];
#pragma unroll
        for (int it = 0; it < 4; ++it)
            af[it] = *(const short8*)(Ato0 + it * 16 * 32);
#pragma unroll
        for (int jt = 0; jt < JT; ++jt)
            bf[jt] = *(const short8*)(Bto0 + jt * 16 * 32);
#pragma unroll
        for (int it = 0; it < 4; ++it)
#pragma unroll
            for (int jt = 0; jt < JT; ++jt)
                acc[it][jt] = __builtin_amdgcn_mfma_f32_16x16x32_bf16(
                    af[it], bf[jt], acc[it][jt], 0, 0, 0);
#pragma unroll
        for (int it = 0; it < 4; ++it)
            af[it] = *(const short8*)(Ato1 + it * 16 * 32);
#pragma unroll
        for (int jt = 0; jt < JT; ++jt)
            bf[jt] = *(const short8*)(Bto1 + jt * 16 * 32);
#pragma unroll
        for (int it = 0; it < 4; ++it)
#pragma unroll
            for (int jt = 0; jt < JT; ++jt)
                acc[it][jt] = __builtin_amdgcn_mfma_f32_16x16x32_bf16(
                    af[it], bf[jt], acc[it][jt], 0, 0, 0);
    }

#pragma unroll
    for (int it = 0; it < 4; ++it)
#pragma unroll
        for (int jt = 0; jt < JT; ++jt)
#pragma unroll
            for (int rg = 0; rg < 4; ++rg) {
                const int m = m0 + wm0 + it * 16 + quad * 4 + rg;
                const int n = n0 + wn0 + jt * 16 + lr;
                float v = acc[it][jt][rg];
                if (EMODE == 0) {
                    float* dst = (float*)(z ? O1v : O0v);
                    if (bias && z == 0) v += bias[n];
                    dst[(size_t)m * N + n] = v;
                } else {
                    v += bias[n];
                    if (ACT == 1) v = fmaxf(v, 0.f);
                    ((ushort_t*)O0v)[(size_t)m * N + n] = f2bf(v);
                }
            }
}

// ---------------------------------------------------------------------------
// Fused QKV + r_net GEMM (BK=32 — known good).
// ---------------------------------------------------------------------------
__global__ __launch_bounds__(256)
void gemm_qkvr(const ushort_t* __restrict__ Acat, const ushort_t* __restrict__ W1,
               const ushort_t* __restrict__ Rsrc, const ushort_t* __restrict__ W2,
               ushort_t* __restrict__ Qac, ushort_t* __restrict__ Qbd,
               ushort_t* __restrict__ Kbf, ushort_t* __restrict__ Vtb,
               ushort_t* __restrict__ Rh,
               const float* __restrict__ rwb, const float* __restrict__ rrb)
{
    __shared__ ushort_t At[128 * 32];
    __shared__ ushort_t Bt[128 * 32];

    const int bid  = blockIdx.x;
    const bool isr = bid >= 768;
    const ushort_t* A; const ushort_t* B; int m0, n0;
    if (!isr) { A = Acat; B = W1; m0 = (bid & 31) * 128; n0 = (bid >> 5) * 128; }
    else { int t = bid - 768; A = Rsrc; B = W2; m0 = (t & 15) * 128; n0 = (t >> 4) * 128; }
    const int K = 1024;

    const int tid  = threadIdx.x;
    const int lane = tid & 63;
    const int w    = tid >> 6;
    const int lr   = lane & 15;
    const int quad = lane >> 4;
    const int wm0  = (w >> 1) * 64;
    const int wn0  = (w & 1) * 64;

    f32x4 acc[4][4];
#pragma unroll
    for (int it = 0; it < 4; ++it)
#pragma unroll
        for (int jt = 0; jt < 4; ++jt) acc[it][jt] = (f32x4){0.f, 0.f, 0.f, 0.f};

    const int srow = lane >> 2;
    const int scol = (lane & 3) << 3;
    const ushort_t* Ag = A + (size_t)(m0 + w * 32 + srow) * K + scol;
    const ushort_t* Bg = B + (size_t)(n0 + w * 32 + srow) * K + scol;
    ushort_t* lA0 = At + (w * 32) * 32;
    ushort_t* lA1 = At + (w * 32 + 16) * 32;
    ushort_t* lB0 = Bt + (w * 32) * 32;
    ushort_t* lB1 = Bt + (w * 32 + 16) * 32;

    const ushort_t* Ato = At + (wm0 + lr) * 32 + quad * 8;
    const ushort_t* Bto = Bt + (wn0 + lr) * 32 + quad * 8;

    for (int k0 = 0; k0 < K; k0 += 32) {
        __syncthreads();
        gload_lds16(Ag + k0, lA0);
        gload_lds16(Ag + (size_t)16 * K + k0, lA1);
        gload_lds16(Bg + k0, lB0);
        gload_lds16(Bg + (size_t)16 * K + k0, lB1);
        __syncthreads();

        short8 af[4], bf[4];
#pragma unroll
        for (int it = 0; it < 4; ++it)
            af[it] = *(const short8*)(Ato + it * 16 * 32);
#pragma unroll
        for (int jt = 0; jt < 4; ++jt)
            bf[jt] = *(const short8*)(Bto + jt * 16 * 32);
#pragma unroll
        for (int it = 0; it < 4; ++it)
#pragma unroll
            for (int jt = 0; jt < 4; ++jt)
                acc[it][jt] = __builtin_amdgcn_mfma_f32_16x16x32_bf16(
                    af[it], bf[jt], acc[it][jt], 0, 0, 0);
    }

#pragma unroll
    for (int it = 0; it < 4; ++it)
#pragma unroll
        for (int jt = 0; jt < 4; ++jt)
#pragma unroll
            for (int rg = 0; rg < 4; ++rg) {
                const int m = m0 + wm0 + it * 16 + quad * 4 + rg;
                const int n = n0 + wn0 + jt * 16 + lr;
                const float v = acc[it][jt][rg];
                if (!isr) {
                    const int j = m >> 1, b = m & 1;
                    const int part = n >> 10, hh = (n >> 6) & 15, d = n & 63;
                    if (part == 0) {
                        if (j >= MLEN) {
                            const int qi = j - MLEN;
                            const size_t qidx = (((size_t)(b * NH + hh)) * QLEN + qi) * DH + d;
                            Qac[qidx] = f2bf(v + rwb[hh * DH + d]);
                            Qbd[qidx] = f2bf(v + rrb[hh * DH + d]);
                        }
                    } else if (part == 1) {
                        Kbf[(((size_t)(b * NH + hh)) * KLEN + j) * DH + d] = f2bf(v);
                    } else {
                        Vtb[(((size_t)(b * NH + hh)) * DH + d) * KLEN + j] = f2bf(v);
                    }
                } else {
                    const int hh = n >> 6, d = n & 63;
                    Rh[(((size_t)hh) * KLEN + m) * DH + d] = f2bf(v);
                }
            }
}

// ---------------------------------------------------------------------------
// MFMA flash attention with TransformerXL rel-shift, split-K x2 (contiguous
// halves so the R window slides 64/chunk -> ring buffer, 2 staging passes).
// LDS = Kt(9216) + Rt ring(18432) + Bw f32(21504) = 49152 B -> 3 blocks/CU.
// V^T chunk is staged INTO the Bw region after softmax (Bw dead by then);
// 3 barriers/chunk. K/V MFMA B-frags come from LDS (round 7's direct-global
// fragments put ~200cyc L2 latency in the MFMA chain: 103 -> 143 us).
// ---------------------------------------------------------------------------
__global__ __launch_bounds__(256, 3)
void attn_mfma(const ushort_t* __restrict__ Qac, const ushort_t* __restrict__ Qbd,
               const ushort_t* __restrict__ Kb, const ushort_t* __restrict__ Vt,
               const ushort_t* __restrict__ Rb,
               float* __restrict__ Op0, float* __restrict__ Op1,
               float* __restrict__ Mp, float* __restrict__ Lp)
{
    __shared__ __align__(16) ushort_t Kt[64 * 72];     //  9216 B
    __shared__ __align__(16) ushort_t Rt[128 * 72];    // 18432 B, ring
    __shared__ __align__(16) float    Bw[4][16][84];   // 21504 B; V^T overlays
    ushort_t* Vl = (ushort_t*)&Bw[0][0][0];            // [64][72] = 9216 B

    const int tid  = threadIdx.x;
    const int lane = tid & 63;
    const int w    = tid >> 6;
    const int lr   = lane & 15;
    const int quad = lane >> 4;
    const int qt   = blockIdx.x;
    const int s    = blockIdx.y;
    const int bh   = blockIdx.z;
    const int i0   = qt << 6;
    const int h    = bh & 15;
    const int b    = bh >> 4;

    short8 qaf[2], qbf[2];
    {
        const size_t rowoff = ((size_t)bh * QLEN + i0 + w * 16 + lr) * DH;
#pragma unroll
        for (int kt = 0; kt < 2; ++kt) {
            qaf[kt] = *(const short8*)(Qac + rowoff + kt * 32 + quad * 8);
            qbf[kt] = *(const short8*)(Qbd + rowoff + kt * 32 + quad * 8);
        }
    }

    f32x4 O[4];
#pragma unroll
    for (int nt = 0; nt < 4; ++nt) O[nt] = (f32x4){0.f, 0.f, 0.f, 0.f};
    float m_run = -3.4e38f, l_run = 0.f;

    const int nc   = qt + 17;
    const int half = (nc + 1) >> 1;
    const int c_lo = s ? half : 0;
    const int c_hi = s ? nc : half;
    const int stw  = 3 - w;
    const float SC = 0.125f * 1.44269504f;   // scale * log2(e)
    const ushort_t* Kh  = Kb + (size_t)bh * KLEN * DH;
    const ushort_t* Vh  = Vt + (size_t)bh * DH * KLEN;
    const ushort_t* Rhp = Rb + (size_t)h * KLEN * DH;

    for (int c = c_lo; c < c_hi; ++c) {
        const int j0 = c << 6;
        const int wb = 960 - i0 + j0;      // window base (global R row of wr=0)

        // stage K chunk (Kt free: its readers finished before prior barrier C)
#pragma unroll
        for (int t = 0; t < 2; ++t) {
            int f = tid + (t << 8);
            int row = f >> 3, c8 = (f & 7) << 3;
            *(int4*)&Kt[row * 72 + c8] = *(const int4*)(Kh + (size_t)(j0 + row) * DH + c8);
        }
        // stage R (ring): first chunk 128 rows, later 64 new rows
        if (c == c_lo) {
#pragma unroll
            for (int t = 0; t < 4; ++t) {
                int f = tid + (t << 8);
                int rl2 = f >> 3, c8 = (f & 7) << 3;
                int g = wb + rl2;
                int gc = g > (KLEN - 1) ? (KLEN - 1) : g;  // clamped rows feed only masked cells
                *(int4*)&Rt[((g) & 127) * 72 + c8] = *(const int4*)(Rhp + (size_t)gc * DH + c8);
            }
        } else {
#pragma unroll
            for (int t = 0; t < 2; ++t) {
                int f = tid + (t << 8);
                int rl2 = (f >> 3) + 64, c8 = (f & 7) << 3;
                int g = wb + rl2;
                int gc = g > (KLEN - 1) ? (KLEN - 1) : g;
                *(int4*)&Rt[((g) & 127) * 72 + c8] = *(const int4*)(Rhp + (size_t)gc * DH + c8);
            }
        }
        __syncthreads();   // B: staging visible

        // BD: 5 window col-tiles -> Bw (f32)
#pragma unroll
        for (int ctl = 0; ctl < 5; ++ctl) {
            const int wr = (stw + ctl) * 16 + lr;
            const int ring = (wb + wr) & 127;
            f32x4 z = (f32x4){0.f, 0.f, 0.f, 0.f};
#pragma unroll
            for (int kt = 0; kt < 2; ++kt) {
                short8 rb2 = *(const short8*)&Rt[ring * 72 + kt * 32 + quad * 8];
                z = __builtin_amdgcn_mfma_f32_16x16x32_bf16(qbf[kt], rb2, z, 0, 0, 0);
            }
#pragma unroll
            for (int rg = 0; rg < 4; ++rg)
                Bw[w][quad * 4 + rg][ctl * 16 + lr] = z[rg];
        }
        // AC: add at shifted col jj + 15 - row
#pragma unroll
        for (int ct = 0; ct < 4; ++ct) {
            f32x4 z = (f32x4){0.f, 0.f, 0.f, 0.f};
#pragma unroll
            for (int kt = 0; kt < 2; ++kt) {
                short8 kb2 = *(const short8*)&Kt[(ct * 16 + lr) * 72 + kt * 32 + quad * 8];
                z = __builtin_amdgcn_mfma_f32_16x16x32_bf16(qaf[kt], kb2, z, 0, 0, 0);
            }
#pragma unroll
            for (int rg = 0; rg < 4; ++rg) {
                const int rrow = quad * 4 + rg;
                Bw[w][rrow][ct * 16 + lr + 15 - rrow] += z[rg];
            }
        }

        // online softmax; lane's 16 probs == its PV A-fragment
        const int lim = i0 + w * 16 + lr + 1024 - j0;
        float pv[16];
        float mx = -3.4e38f;
#pragma unroll
        for (int kt = 0; kt < 2; ++kt)
#pragma unroll
            for (int t = 0; t < 8; ++t) {
                const int jj = kt * 32 + quad * 8 + t;
                float sv = Bw[w][lr][jj + 15 - lr] * SC;
                sv = (jj > lim) ? -3.4e38f : sv;
                pv[kt * 8 + t] = sv;
                mx = fmaxf(mx, sv);
            }
        mx = fmaxf(mx, __shfl_xor(mx, 16, 64));
        mx = fmaxf(mx, __shfl_xor(mx, 32, 64));
        const float m_new = fmaxf(m_run, mx);
        float ps = 0.f;
        short8 pf[2];
#pragma unroll
        for (int kt = 0; kt < 2; ++kt)
#pragma unroll
            for (int t = 0; t < 8; ++t) {
                const float e = exp2f(pv[kt * 8 + t] - m_new);
                ps += e;
                pf[kt][t] = (short)f2bf(e);
            }
        ps += __shfl_xor(ps, 16, 64);
        ps += __shfl_xor(ps, 32, 64);
        const float alpha = exp2f(m_run - m_new);
        m_run = m_new;
        l_run = l_run * alpha + ps;

        __syncthreads();   // C: all Bw reads + Kt reads done

        // stage V^T chunk into the (dead) Bw region
#pragma unroll
        for (int t = 0; t < 2; ++t) {
            int f = tid + (t << 8);
            int d = f >> 3, c8 = (f & 7) << 3;
            *(int4*)&Vl[d * 72 + c8] = *(const int4*)(Vh + (size_t)d * KLEN + j0 + c8);
        }
        __syncthreads();   // D: V visible

        float ar[4];
#pragma unroll
        for (int rg = 0; rg < 4; ++rg)
            ar[rg] = __shfl(alpha, quad * 4 + rg, 64);
#pragma unroll
        for (int nt = 0; nt < 4; ++nt) {
            O[nt][0] *= ar[0]; O[nt][1] *= ar[1];
            O[nt][2] *= ar[2]; O[nt][3] *= ar[3];
        }
#pragma unroll
        for (int kt = 0; kt < 2; ++kt)
#pragma unroll
            for (int nt = 0; nt < 4; ++nt) {
                short8 vb = *(const short8*)&Vl[(nt * 16 + lr) * 72 + kt * 32 + quad * 8];
                O[nt] = __builtin_amdgcn_mfma_f32_16x16x32_bf16(pf[kt], vb, O[nt], 0, 0, 0);
            }
    }

    if (quad == 0) {
        const size_t mi = ((size_t)s * 32 + bh) * QLEN + i0 + w * 16 + lr;
        Mp[mi] = m_run;
        Lp[mi] = l_run;
    }
    float* Op = s ? Op1 : Op0;
#pragma unroll
    for (int nt = 0; nt < 4; ++nt)
#pragma unroll
        for (int rg = 0; rg < 4; ++rg) {
            const int i = i0 + w * 16 + quad * 4 + rg;
            Op[((size_t)i * BSZc + b) * DM + h * DH + nt * 16 + lr] = O[nt][rg];
        }
}

// ---------------------------------------------------------------------------
// merge split-K partials -> bf16 attn_vec
// ---------------------------------------------------------------------------
__global__ __launch_bounds__(256)
void attn_merge(const float* __restrict__ O0, const float* __restrict__ O1,
                const float* __restrict__ Mp, const float* __restrict__ Lp,
                ushort_t* __restrict__ AV)
{
    const int row = blockIdx.x;           // i*BSZ + b
    const int tid = threadIdx.x;
    const int i = row >> 1, b = row & 1;
    const int h = tid >> 4;
    const int bh = b * NH + h;
    const size_t mi = (size_t)bh * QLEN + i;
    const float m1 = Mp[mi],             l1 = Lp[mi];
    const float m2 = Mp[32 * QLEN + mi], l2 = Lp[32 * QLEN + mi];
    const float M = fmaxf(m1, m2);
    const float a1 = exp2f(m1 - M), a2 = exp2f(m2 - M);
    const float rl = 1.f / (l1 * a1 + l2 * a2);
    const float f1 = a1 * rl, f2 = a2 * rl;
    const float4 o1 = ((const float4*)(O0 + (size_t)row * DM))[tid];
    const float4 o2 = ((const float4*)(O1 + (size_t)row * DM))[tid];
    ushort_t* p = AV + (size_t)row * DM + tid * 4;
    p[0] = f2bf(o1.x * f1 + o2.x * f2);
    p[1] = f2bf(o1.y * f1 + o2.y * f2);
    p[2] = f2bf(o1.z * f1 + o2.z * f2);
    p[3] = f2bf(o1.w * f1 + o2.w * f2);
}

// ---------------------------------------------------------------------------
// out = LayerNorm(X + Y0 [+ Y1]); optional bf16 secondary output
// ---------------------------------------------------------------------------
__global__ __launch_bounds__(256)
void add_ln(const float* __restrict__ X, const float* __restrict__ Y0,
            const float* __restrict__ Y1,
            const float* __restrict__ gg, const float* __restrict__ bb,
            float* __restrict__ out, ushort_t* __restrict__ outb)
{
    const int row  = blockIdx.x;
    const int tid  = threadIdx.x;
    const int lane = tid & 63;
    const int w    = tid >> 6;
    __shared__ float ssum[4], ssq[4];

    const float4 xv = ((const float4*)(X + (size_t)row * DM))[tid];
    const float4 yv = ((const float4*)(Y0 + (size_t)row * DM))[tid];
    float v0 = xv.x + yv.x, v1 = xv.y + yv.y;
    float v2 = xv.z + yv.z, v3 = xv.w + yv.w;
    if (Y1) {
        const float4 zv = ((const float4*)(Y1 + (size_t)row * DM))[tid];
        v0 += zv.x; v1 += zv.y; v2 += zv.z; v3 += zv.w;
    }
    float s = v0 + v1 + v2 + v3;
    float q = v0 * v0 + v1 * v1 + v2 * v2 + v3 * v3;
#pragma unroll
    for (int off = 32; off > 0; off >>= 1) {
        s += __shfl_xor(s, off, 64);
        q += __shfl_xor(q, off, 64);
    }
    if (lane == 0) { ssum[w] = s; ssq[w] = q; }
    __syncthreads();
    s = ssum[0] + ssum[1] + ssum[2] + ssum[3];
    q = ssq[0] + ssq[1] + ssq[2] + ssq[3];
    const float mean = s * (1.f / DM);
    const float var  = q * (1.f / DM) - mean * mean;
    const float rs   = rsqrtf(var + 1e-5f);
    const float4 g4 = ((const float4*)gg)[tid];
    const float4 b4 = ((const float4*)bb)[tid];
    float4 ov;
    ov.x = (v0 - mean) * rs * g4.x + b4.x;
    ov.y = (v1 - mean) * rs * g4.y + b4.y;
    ov.z = (v2 - mean) * rs * g4.z + b4.z;
    ov.w = (v3 - mean) * rs * g4.w + b4.w;
    ((float4*)(out + (size_t)row * DM))[tid] = ov;
    if (outb) {
        ushort_t* p = outb + (size_t)row * DM + tid * 4;
        p[0] = f2bf(ov.x); p[1] = f2bf(ov.y);
        p[2] = f2bf(ov.z); p[3] = f2bf(ov.w);
    }
}

// ---------------------------------------------------------------------------
extern "C" void kernel_launch(void* const* d_in, const int* in_sizes, int n_in,
                              void* d_out, int out_size, void* d_ws, size_t ws_size,
                              hipStream_t stream)
{
    (void)in_sizes; (void)n_in; (void)out_size; (void)ws_size;
    const float* w      = (const float*)d_in[0];
    const float* r      = (const float*)d_in[1];
    const float* mems   = (const float*)d_in[2];
    // d_in[3] attn_mask: deterministic (j > i + MLEN), applied analytically
    const float* qkv_w  = (const float*)d_in[4];
    const float* rnet_w = (const float*)d_in[5];
    const float* o_w    = (const float*)d_in[6];
    const float* r_r_b  = (const float*)d_in[7];
    const float* r_w_b  = (const float*)d_in[8];
    const float* ln1g   = (const float*)d_in[9];
    const float* ln1b   = (const float*)d_in[10];
    const float* ffw1   = (const float*)d_in[11];
    const float* ffb1   = (const float*)d_in[12];
    const float* ffw2   = (const float*)d_in[13];
    const float* ffb2   = (const float*)d_in[14];
    const float* ln2g   = (const float*)d_in[15];
    const float* ln2b   = (const float*)d_in[16];
    float* out = (float*)d_out;

    char* wsb = (char*)d_ws;
    const size_t MB = 1024 * 1024;
    // ---- workspace layout, live ranges verified against launch order ----
    ushort_t* W1    = (ushort_t*)(wsb + 0 * MB);   // 0-6    dead after qkvr
    ushort_t* W2    = (ushort_t*)(wsb + 6 * MB);   // 6-8    dead after qkvr
    ushort_t* Acat  = (ushort_t*)(wsb + 8 * MB);   // 8-16   dead after qkvr
    ushort_t* Rsrc  = (ushort_t*)(wsb + 16 * MB);  // 16-20  dead after qkvr
    ushort_t* Qac   = (ushort_t*)(wsb + 20 * MB);  // 20-24  dead after attn
    ushort_t* Qbd   = (ushort_t*)(wsb + 24 * MB);  // 24-28  dead after attn
    ushort_t* Kbf   = (ushort_t*)(wsb + 28 * MB);  // 28-36  dead after attn
    ushort_t* Vt    = (ushort_t*)(wsb + 36 * MB);  // 36-44  dead after attn
    ushort_t* Rh    = (ushort_t*)(wsb + 44 * MB);  // 44-48  dead after attn
    float*    Op0   = (float*)(wsb + 48 * MB);     // 48-56  attn -> merge
    float*    Op1   = (float*)(wsb + 56 * MB);     // 56-64  attn -> merge
    float*    Mp    = (float*)(wsb + 4 * MB);      // 4-4.25 (over dead W1)
    float*    Lp    = (float*)(wsb + 4 * MB + 512 * 1024); // 4.5-4.75
    ushort_t* AVec  = (ushort_t*)(wsb + 0 * MB);   // 0-4   merge -> o-proj
    ushort_t* W3    = (ushort_t*)(wsb + 4 * MB);   // 4-6   cast2 -> o-proj (over Mp/Lp dead)
    float*    AOut0 = (float*)(wsb + 8 * MB);      // 8-16  o-proj -> ln1 (over Acat dead)
    float*    AOut1 = (float*)(wsb + 44 * MB);     // 44-52 o-proj -> ln1 (over Rh/Op0-head dead)
    float*    Hbuf  = (float*)(wsb + 16 * MB);     // 16-24 ln1 -> ln2 (over Rsrc/Qac dead)
    ushort_t* Hbf   = (ushort_t*)(wsb + 24 * MB);  // 24-28 ln1 -> ff1 (over Qbd dead)
    ushort_t* W4    = (ushort_t*)(wsb + 28 * MB);  // 28-36 cast2 -> ff1 (over Kbf dead)
    ushort_t* FFbf  = (ushort_t*)(wsb + 36 * MB);  // 36-52 ff1 -> ff2 (over Vt/AOut1 dead)
    ushort_t* W5    = (ushort_t*)(wsb + 52 * MB);  // 52-60 cast2 -> ff2 (over Op0-tail/Op1-head dead)
    float*    Core0 = (float*)(wsb + 0 * MB);      // 0-8   ff2 -> ln2 (AVec/W3 dead)
    float*    Core1 = (float*)(wsb + 8 * MB);      // 8-16  ff2 -> ln2 (AOut0 dead)
    // peak 64 MB

    dim3 blk(256);

    // casts for phase 1
    cast_phase1<<<dim3(5120), blk, 0, stream>>>(qkv_w, rnet_w, mems, w, r,
                                                W1, W2, Acat, Rsrc);

    // 1+2. fused QKV + r_net projections
    gemm_qkvr<<<dim3(896), blk, 0, stream>>>(
        Acat, W1, Rsrc, W2, Qac, Qbd, Kbf, Vt, Rh, r_w_b, r_r_b);

    // 3. MFMA flash attention, split-K x2 (contiguous halves) -> partials
    attn_mfma<<<dim3(16, 2, 32), blk, 0, stream>>>(
        Qac, Qbd, Kbf, Vt, Rh, Op0, Op1, Mp, Lp);

    // 3b. merge partials -> bf16 attn_vec
    attn_merge<<<dim3(2048), blk, 0, stream>>>(Op0, Op1, Mp, Lp, AVec);

    // casts for phase 2
    cast_phase2<<<dim3(4608), blk, 0, stream>>>(o_w, ffw1, ffw2, W3, W4, W5);

    // 4. output projection, split-K x2 (f32 partials)
    gemm_mfma<0, 0, 64, 2><<<dim3(16, 16, 2), blk, 0, stream>>>(
        AVec, W3, nullptr, AOut0, AOut1, 2048, 1024, 512, 1024, 1024);

    // 5. h = LN(w + AOut0 + AOut1)  (f32 + bf16 copies)
    add_ln<<<dim3(2 * QLEN), blk, 0, stream>>>(w, AOut0, AOut1, ln1g, ln1b, Hbuf, Hbf);

    // 6. FF1: relu(h @ ff_w1^T + b1) -> bf16
    gemm_mfma<3, 1, 128, 1><<<dim3(16, 32), blk, 0, stream>>>(
        Hbf, W4, ffb1, FFbf, nullptr, 2048, 4096, 1024, 1024, 1024);

    // 7. FF2, split-K x2 -> f32 partials
    gemm_mfma<0, 0, 64, 2><<<dim3(16, 16, 2), blk, 0, stream>>>(
        FFbf, W5, ffb2, Core0, Core1, 2048, 1024, 2048, 4096, 4096);

    // 8. out = LN(h + Core0 + Core1)
    add_ln<<<dim3(2 * QLEN), blk, 0, stream>>>(Hbuf, Core0, Core1, ln2g, ln2b, out, nullptr);
}